// Round 11
// baseline (3027.782 us; speedup 1.0000x reference)
//
#include <hip/hip_runtime.h>
#include <hip/hip_bf16.h>
#include <type_traits>

// LSTM decoder B=256, T=512, H=1024 — persistent fp16 MFMA, v14.
// R10 falsified the spill theory (asm-forced loads: VGPR still 120, perf
// unchanged, FETCH tiny -> B was already resident via AGPRs; VGPR_Count is
// arch-only). Remaining big removable cost: Wlds LDS port traffic (262KB/
// step/CU of ds_read_b128 inside the MFMA stream) + B-residency ceiling at
// 2 waves/SIMD. v14: 4 waves x 512 regs. WG = 256 thr (grid 256, 1 WG/CU,
// launch_bounds(256,1) + waves_per_eu(1,1)). Each wave = K-quarter, both
// m-halves, ALL 4 gates x 2 nt in registers: Breg[8][4][2]=256 + ring 64 +
// acc 64 + consts ~40 = ~440 < 512. Wlds DELETED (zero LDS in K-loop);
// LDS = 32KB scr only. Split-K = v8's proven 3-phase algebra (acc now
// [m2][g][nt]); epilogue 4 j/thread -> one coalesced dwordx2 h-store
// (thread's 4 fp16 = exactly one u64 unit). Fastmode (XCD-local h, proven
// WRITE 266MB->5MB) + barrier + spin budget byte-identical to v10.3.

#define BB 256
#define TT 512
#define HH 1024

typedef __attribute__((ext_vector_type(8))) short short8;
typedef __attribute__((ext_vector_type(8))) _Float16 half8;
typedef __attribute__((ext_vector_type(4))) float float4v;

#define HP_U64 ((size_t)65536)   // u64 per h buffer: 256 U-units x 256 rows

__device__ __forceinline__ float sigf(float x) { return 1.0f / (1.0f + __expf(-x)); }
__device__ __forceinline__ float tanhff(float x) {
    return 1.0f - 2.0f / (__expf(2.0f * x) + 1.0f);
}

// ---- pack W_hh (4096x1024 f32) -> fp16 B-fragment order (UNCHANGED) ----
// Wp[jt2(32)][kc(32)][g(4)][nt(2)][lane(64)][8] ; per-jt2 block = 256 KB
__global__ __launch_bounds__(256) void pack_w(const float* __restrict__ W_hh,
                                              unsigned short* __restrict__ Wp) {
    int fid = blockIdx.x * 256 + threadIdx.x;   // 0..524287
    int lane = fid & 63;
    int nt = (fid >> 6) & 1;
    int g = (fid >> 7) & 3;
    int kc = (fid >> 9) & 31;
    int jt2 = fid >> 14;
    int j = jt2 * 32 + nt * 16 + (lane & 15);
    int row = g * HH + j;
    int k = kc * 32 + (lane >> 4) * 8;
    const float* src = W_hh + (size_t)row * HH + k;
    union { _Float16 h[8]; short8 s; } u;
#pragma unroll
    for (int e = 0; e < 8; ++e) u.h[e] = (_Float16)src[e];
    *(short8*)(Wp + (size_t)fid * 8) = u.s;
}

// ---- h0 -> fp16 fragment layout in buffer 0; zero barrier counters (UNCHANGED) ----
// unit U=(k>>5)*8+((k>>2)&7); u64 idx = U*256 + M  (boff == M)
__global__ __launch_bounds__(256) void prep_state(const float* __restrict__ h0,
                                                  unsigned long long* __restrict__ hb0,
                                                  unsigned int* __restrict__ cnt) {
    int gid = blockIdx.x * 256 + threadIdx.x;   // 0..65535
    int r = gid & 255;
    int U = gid >> 8;
    int kb = (U >> 3) * 32 + ((U >> 1) & 3) * 8 + (U & 1) * 4;
    float4 v = *(const float4*)(h0 + (size_t)r * HH + kb);
    union { _Float16 h[4]; unsigned long long u; } x;
    x.h[0] = (_Float16)v.x; x.h[1] = (_Float16)v.y;
    x.h[2] = (_Float16)v.z; x.h[3] = (_Float16)v.w;
    hb0[(size_t)U * 256 + r] = x.u;
    if (blockIdx.x == 0) cnt[threadIdx.x] = 0;   // per-group {bar, mask, arrive}
}

// ---- persistent LSTM kernel: all 512 steps + final FC ----
__global__ __launch_bounds__(256, 1)
__attribute__((amdgpu_waves_per_eu(1, 1)))
void lstm_persist(
    const float* __restrict__ y_hist,
    const float* __restrict__ W_ih,           // (4096) flat
    const float* __restrict__ b_ih,
    const float* __restrict__ b_hh,
    const float* __restrict__ c0,             // (B,H) f32
    const float* __restrict__ W_fc,           // (H)
    const float* __restrict__ b_fc,           // (1)
    const unsigned short* __restrict__ Wp,    // packed fp16 W fragments
    unsigned long long* hbase,                // 2 buffers x HP_U64 u64
    unsigned int* cnt,
    float* __restrict__ out)
{
    __shared__ __align__(16) float scr[8192];   // 32 KB: 4 regions x 2048
    // 32 KiB LDS; VGPR ~440 -> 1 wave/SIMD -> 1 WG/CU; grid=256 co-resident

    const int tid = threadIdx.x;               // 0..255
    const int lane = tid & 63;
    const int k4 = tid >> 6;                   // wave = K quarter 0..3
    const int bid = blockIdx.x;
    const int gm = bid & 7;                    // m-group == XCD id (round-robin)
    const int jt2 = bid >> 3;                  // 32-j tile 0..31

    const unsigned short* WpJ = Wp + (size_t)jt2 * 131072;

    // --- B FULLY in registers: 8 chunks x 4 gates x 2 nt = 64 half8 = 256 regs ---
    half8 Breg[8][4][2];
#pragma unroll
    for (int ch = 0; ch < 8; ++ch) {
        int kc = k4 * 8 + ch;
#pragma unroll
        for (int g = 0; g < 4; ++g)
#pragma unroll
            for (int nt = 0; nt < 2; ++nt)
                Breg[ch][g][nt] = *(const half8*)
                    (WpJ + (size_t)((((kc * 4 + g) * 2 + nt) * 64 + lane)) * 8);
    }

    // --- A addressing (both m halves per wave) ---
    const int q = lane >> 4;
    const size_t abase = (size_t)gm * 32 + (lane & 15);   // + m2*16
    const size_t qoff = (size_t)q * 512;
    const int ml = q * 4;                      // row quad within 16-row tile

    // --- epilogue constants (256 threads: 1 row x 4 j each) ---
    const int em = tid & 31;                   // tile-local row
    const int jp = tid >> 5;                   // j-quad 0..7
    const int M = gm * 32 + em;
    float wi_[4][4], bs_[4][4], c_[4];
#pragma unroll
    for (int g = 0; g < 4; ++g)
#pragma unroll
        for (int jj = 0; jj < 4; ++jj) {
            int j = jt2 * 32 + jp * 4 + jj;
            wi_[g][jj] = W_ih[g * HH + j];
            bs_[g][jj] = b_ih[g * HH + j] + b_hh[g * HH + j];
        }
#pragma unroll
    for (int jj = 0; jj < 4; ++jj)
        c_[jj] = c0[(size_t)M * HH + jt2 * 32 + jp * 4 + jj];
    // thread's 4 fp16 = u64 unit U = jt2*8+jp at row M; wave = 512B contiguous
    const size_t hidx = (size_t)(jt2 * 8 + jp) * 256 + M;

    unsigned int* mycnt = cnt + gm * 32;       // [0]=barrier [1]=xcd mask [2]=arrive

    // --- spin budget: hang-proofing (v10.3-proven) ---
    unsigned spin_budget = 1u << 20;

    // --- XCD-uniformity detection (device-scope, once). Bailout -> SAFE. ---
    if (tid == 0) {
        unsigned myxcd;
        asm volatile("s_getreg_b32 %0, hwreg(HW_REG_XCC_ID)" : "=s"(myxcd));
        __hip_atomic_fetch_or(mycnt + 1, 1u << (myxcd & 31u),
                              __ATOMIC_RELAXED, __HIP_MEMORY_SCOPE_AGENT);
        __hip_atomic_fetch_add(mycnt + 2, 1u,
                               __ATOMIC_RELAXED, __HIP_MEMORY_SCOPE_AGENT);
        int ok = 0;
        while (spin_budget) {
            if (__hip_atomic_load(mycnt + 2, __ATOMIC_RELAXED,
                                  __HIP_MEMORY_SCOPE_AGENT) >= 32u) { ok = 1; break; }
            __builtin_amdgcn_s_sleep(1);
            --spin_budget;
        }
        unsigned mm = __hip_atomic_load(mycnt + 1, __ATOMIC_RELAXED,
                                        __HIP_MEMORY_SCOPE_AGENT);
        ((volatile int*)scr)[0] = (ok && ((mm & (mm - 1u)) == 0u)) ? 1 : 0;
    }
    __syncthreads();
    const bool fastmode = (((volatile int*)scr)[0] != 0);
    __syncthreads();   // flag captured before scr reuse

    auto mainloop = [&](auto FASTC) {
        constexpr bool FAST = decltype(FASTC)::value;
        for (int t = 0; t < TT; ++t) {
            const unsigned long long* hR = hbase + (size_t)(t & 1) * HP_U64;
            unsigned long long* hW = hbase + (size_t)((t + 1) & 1) * HP_U64;

            float x = y_hist[(size_t)M * TT + t];   // epilogue input, prefetched

            float4v acc[2][4][2];
#pragma unroll
            for (int m2 = 0; m2 < 2; ++m2)
#pragma unroll
                for (int g = 0; g < 4; ++g)
#pragma unroll
                    for (int nt = 0; nt < 2; ++nt)
                        acc[m2][g][nt] = (float4v){0.f, 0.f, 0.f, 0.f};

            // --- sync-free K-loop: 8 chunks of K=32, full 8-deep prefetch ---
            unsigned long long ring[8][2][2];   // [p][m2][pair]
            if constexpr (FAST) {
                // sc1: device scope — probes the (same-XCD) L2, hits dirty
                // lines from fastmode stores; bypasses possibly-stale L1.
#pragma unroll
                for (int p = 0; p < 8; ++p) {
                    size_t base = (size_t)(k4 * 8 + p) * 2048 + qoff + abase;
#pragma unroll
                    for (int m2 = 0; m2 < 2; ++m2) {
                        asm volatile("global_load_dwordx2 %0, %1, off sc1"
                                     : "=v"(ring[p][m2][0]) : "v"(&hR[base + m2 * 16]));
                        asm volatile("global_load_dwordx2 %0, %1, off sc1"
                                     : "=v"(ring[p][m2][1]) : "v"(&hR[base + m2 * 16 + 256]));
                    }
                }
                asm volatile("s_waitcnt vmcnt(0)" ::: "memory");
                __builtin_amdgcn_sched_barrier(0);   // rule #18: pin uses after wait
            } else {
#pragma unroll
                for (int p = 0; p < 8; ++p) {
                    size_t base = (size_t)(k4 * 8 + p) * 2048 + qoff + abase;
#pragma unroll
                    for (int m2 = 0; m2 < 2; ++m2) {
                        ring[p][m2][0] = __hip_atomic_load(
                            (unsigned long long*)&hR[base + m2 * 16],
                            __ATOMIC_RELAXED, __HIP_MEMORY_SCOPE_AGENT);
                        ring[p][m2][1] = __hip_atomic_load(
                            (unsigned long long*)&hR[base + m2 * 16 + 256],
                            __ATOMIC_RELAXED, __HIP_MEMORY_SCOPE_AGENT);
                    }
                }
            }
#pragma unroll
            for (int ch = 0; ch < 8; ++ch) {
                union { unsigned long long u[2]; half8 h; } af0, af1;
                af0.u[0] = ring[ch][0][0]; af0.u[1] = ring[ch][0][1];
                af1.u[0] = ring[ch][1][0]; af1.u[1] = ring[ch][1][1];
#pragma unroll
                for (int g = 0; g < 4; ++g)
#pragma unroll
                    for (int nt = 0; nt < 2; ++nt) {
                        acc[0][g][nt] = __builtin_amdgcn_mfma_f32_16x16x32_f16(
                            af0.h, Breg[ch][g][nt], acc[0][g][nt], 0, 0, 0);
                        acc[1][g][nt] = __builtin_amdgcn_mfma_f32_16x16x32_f16(
                            af1.h, Breg[ch][g][nt], acc[1][g][nt], 0, 0, 0);
                    }
            }

            // --- 4-way k-reduction, v8's proven 3-phase scheme (acc[m2][g][nt]) ---
            if (k4 >= 2) {
#pragma unroll
                for (int m2 = 0; m2 < 2; ++m2)
#pragma unroll
                    for (int g = 0; g < 4; ++g)
#pragma unroll
                        for (int nt = 0; nt < 2; ++nt) {
                            int n = g * 32 + nt * 16 + (lane & 15);
                            *(float4v*)&scr[(m2 * 2 + (k4 & 1)) * 2048 + n * 16 +
                                            (ml ^ ((n & 3) << 2))] = acc[m2][g][nt];
                        }
            }
            __syncthreads();
            if (k4 < 2) {
#pragma unroll
                for (int m2 = 0; m2 < 2; ++m2)
#pragma unroll
                    for (int g = 0; g < 4; ++g)
#pragma unroll
                        for (int nt = 0; nt < 2; ++nt) {
                            int n = g * 32 + nt * 16 + (lane & 15);
                            acc[m2][g][nt] += *(const float4v*)
                                &scr[(m2 * 2 + k4) * 2048 + n * 16 + (ml ^ ((n & 3) << 2))];
                        }
                if (k4 == 1) {
#pragma unroll
                    for (int m2 = 0; m2 < 2; ++m2)
#pragma unroll
                        for (int g = 0; g < 4; ++g)
#pragma unroll
                            for (int nt = 0; nt < 2; ++nt) {
                                int n = g * 32 + nt * 16 + (lane & 15);
                                *(float4v*)&scr[(m2 * 2 + 1) * 2048 + n * 16 +
                                                (ml ^ ((n & 3) << 2))] = acc[m2][g][nt];
                            }
                }
            }
            __syncthreads();
            if (k4 == 0) {
#pragma unroll
                for (int m2 = 0; m2 < 2; ++m2)
#pragma unroll
                    for (int g = 0; g < 4; ++g)
#pragma unroll
                        for (int nt = 0; nt < 2; ++nt) {
                            int n = g * 32 + nt * 16 + (lane & 15);
                            int sw = n * 16 + (ml ^ ((n & 3) << 2));
                            acc[m2][g][nt] += *(const float4v*)&scr[(m2 * 2 + 1) * 2048 + sw];
                            *(float4v*)&scr[(m2 * 2) * 2048 + sw] = acc[m2][g][nt];
                        }
            }
            __syncthreads();

            // --- epilogue (256 threads): 1 row x 4 j; ONE dwordx2 h-store ---
            {
                int rbase = (em >> 4) * 2 * 2048;
                union { _Float16 h[4]; unsigned long long u; } hv;
#pragma unroll
                for (int jj = 0; jj < 4; ++jj) {
                    int jl = jp * 4 + jj;                      // 0..31
                    int msw = (em & 15) ^ ((jl & 3) << 2);
                    float gi = scr[rbase + (0 * 32 + jl) * 16 + msw] + x * wi_[0][jj] + bs_[0][jj];
                    float gf = scr[rbase + (1 * 32 + jl) * 16 + msw] + x * wi_[1][jj] + bs_[1][jj];
                    float gg = scr[rbase + (2 * 32 + jl) * 16 + msw] + x * wi_[2][jj] + bs_[2][jj];
                    float go = scr[rbase + (3 * 32 + jl) * 16 + msw] + x * wi_[3][jj] + bs_[3][jj];
                    float cn = sigf(gf) * c_[jj] + sigf(gi) * tanhff(gg);
                    float hn = sigf(go) * tanhff(cn);
                    c_[jj] = cn;
                    hv.h[jj] = (_Float16)hn;
                }
                if constexpr (FAST)
                    asm volatile("global_store_dwordx2 %0, %1, off sc0"
                                 : : "v"((void*)(hW + hidx)), "v"(hv.u) : "memory");
                else
                    asm volatile("global_store_dwordx2 %0, %1, off sc0 sc1"
                                 : : "v"((void*)(hW + hidx)), "v"(hv.u) : "memory");
            }

            // --- drain stores, then m-group barrier (32 WGs, budget-bounded) ---
            asm volatile("s_waitcnt vmcnt(0)" ::: "memory");
            __syncthreads();
            if (tid == 0) {
                unsigned target = 32u * (unsigned)(t + 1);
                if constexpr (FAST) {
                    __hip_atomic_fetch_add(mycnt, 1u, __ATOMIC_RELAXED,
                                           __HIP_MEMORY_SCOPE_WORKGROUP);
                    while (spin_budget &&
                           __hip_atomic_load(mycnt, __ATOMIC_RELAXED,
                                             __HIP_MEMORY_SCOPE_AGENT) < target) {
                        __builtin_amdgcn_s_sleep(1);
                        --spin_budget;
                    }
                } else {
                    __hip_atomic_fetch_add(mycnt, 1u, __ATOMIC_RELAXED,
                                           __HIP_MEMORY_SCOPE_AGENT);
                    while (spin_budget &&
                           __hip_atomic_load(mycnt, __ATOMIC_RELAXED,
                                             __HIP_MEMORY_SCOPE_AGENT) < target) {
                        __builtin_amdgcn_s_sleep(1);
                        --spin_budget;
                    }
                }
            }
            __syncthreads();
        }
    };
    if (fastmode) mainloop(std::integral_constant<bool, true>{});
    else          mainloop(std::integral_constant<bool, false>{});

    // --- final FC (h final in buffer 0): jt2==0 WGs, wave 0 (32 rows) ---
    if (jt2 == 0 && k4 == 0) {
        const unsigned long long* hF = hbase;   // buffer 0
#pragma unroll 1
        for (int rr = 0; rr < 32; ++rr) {
            int row = gm * 32 + rr;
            int boff = row;
            float s = 0.f;
#pragma unroll 1
            for (int uu = 0; uu < 4; ++uu) {
                int U = uu * 64 + lane;
                unsigned long long u;
                if (fastmode) {
                    asm volatile("global_load_dwordx2 %0, %1, off sc1\n\ts_waitcnt vmcnt(0)"
                                 : "=v"(u) : "v"(&hF[(size_t)U * 256 + boff]) : "memory");
                } else {
                    u = __hip_atomic_load((unsigned long long*)&hF[(size_t)U * 256 + boff],
                                          __ATOMIC_RELAXED, __HIP_MEMORY_SCOPE_AGENT);
                }
                int kb = (U >> 3) * 32 + ((U >> 1) & 3) * 8 + (U & 1) * 4;
                union { _Float16 h[4]; unsigned long long x; } v;
                v.x = u;
                float4 wf = *(const float4*)(W_fc + kb);
                s += (float)v.h[0] * wf.x + (float)v.h[1] * wf.y +
                     (float)v.h[2] * wf.z + (float)v.h[3] * wf.w;
            }
#pragma unroll
            for (int off = 32; off > 0; off >>= 1) s += __shfl_xor(s, off);
            if (lane == 0) out[row] = s + b_fc[0];
        }
    }
}

extern "C" void kernel_launch(void* const* d_in, const int* in_sizes, int n_in,
                              void* d_out, int out_size, void* d_ws, size_t ws_size,
                              hipStream_t stream) {
    const float* y_hist = (const float*)d_in[0];
    const float* W_ih   = (const float*)d_in[1];
    const float* W_hh   = (const float*)d_in[2];
    const float* b_ih   = (const float*)d_in[3];
    const float* b_hh   = (const float*)d_in[4];
    const float* W_fc   = (const float*)d_in[5];
    const float* b_fc   = (const float*)d_in[6];
    const float* h0     = (const float*)d_in[7];
    const float* c0     = (const float*)d_in[8];
    float* out = (float*)d_out;

    // ws: Wp fp16 (8 MB) | h buffers 2 x 512 KB | cnt (1 KB)
    unsigned short* Wp = (unsigned short*)d_ws;
    unsigned long long* hbase = (unsigned long long*)(Wp + (size_t)4194304);
    unsigned int* cnt = (unsigned int*)(hbase + 2 * HP_U64);

    pack_w<<<2048, 256, 0, stream>>>(W_hh, Wp);
    prep_state<<<256, 256, 0, stream>>>(h0, hbase, cnt);

    // 256 WGs x 256 threads, 32 KiB LDS, 512-reg waves -> 1 WG/CU co-resident
    lstm_persist<<<256, 256, 0, stream>>>(y_hist, W_ih, b_ih, b_hh, c0, W_fc, b_fc,
                                          Wp, hbase, cnt, out);
}

// Round 12
// 2108.322 us; speedup vs baseline: 1.4361x; 1.4361x over previous
//
#include <hip/hip_runtime.h>
#include <hip/hip_bf16.h>
#include <type_traits>

// LSTM decoder B=256, T=512, H=1024 — persistent fp16 MFMA, v15.
// Base = v10.3 config (2365 us proven: 512 thr, 160KB LDS, 120 VGPR,
// XCD-local h). R11 evidence: v14 (1 wave/SIMD) showed wave parallelism is
// the binding resource -> kernel is sync-bound; the monolithic 32-WG barrier
// (32 serialized RMWs on ONE L2 address + sleep-poll) costs ~1.5-2k cy/step.
// Structural fact (index algebra): h-chunk kc is produced EXACTLY by WG
// jt2==kc; consumer wave k4 needs only producers jt2 in [8*k4, 8*k4+8).
// v15 fastmode: dataflow flags — producer stores flag[gm][jt2]=t+1 (plain
// sc0 store, no RMW chain); consumer wave polls ITS 8 flags (sc1) and
// proceeds. Run-ahead self-limits to 1 step (a WG's 4 waves collectively
// need all 32 flags) -> 2 h-buffers stay WAW-safe. FC tail polls all 32
// flags >= 512. Safe mode = v8 monolithic barrier, byte-identical. Spin
// budgets everywhere (hang-proof).

#define BB 256
#define TT 512
#define HH 1024

typedef __attribute__((ext_vector_type(8))) short short8;
typedef __attribute__((ext_vector_type(8))) _Float16 half8;
typedef __attribute__((ext_vector_type(4))) float float4v;

#define HP_U64 ((size_t)65536)   // u64 per h buffer: 256 U-units x 256 rows

__device__ __forceinline__ float sigf(float x) { return 1.0f / (1.0f + __expf(-x)); }
__device__ __forceinline__ float tanhff(float x) {
    return 1.0f - 2.0f / (__expf(2.0f * x) + 1.0f);
}

// ---- pack W_hh (4096x1024 f32) -> fp16 B-fragment order ----
// Wp[jt2(32)][kc(32)][g(4)][nt(2)][lane(64)][8] ; per-jt2 block = 256 KB
__global__ __launch_bounds__(256) void pack_w(const float* __restrict__ W_hh,
                                              unsigned short* __restrict__ Wp) {
    int fid = blockIdx.x * 256 + threadIdx.x;   // 0..524287
    int lane = fid & 63;
    int nt = (fid >> 6) & 1;
    int g = (fid >> 7) & 3;
    int kc = (fid >> 9) & 31;
    int jt2 = fid >> 14;
    int j = jt2 * 32 + nt * 16 + (lane & 15);
    int row = g * HH + j;
    int k = kc * 32 + (lane >> 4) * 8;
    const float* src = W_hh + (size_t)row * HH + k;
    union { _Float16 h[8]; short8 s; } u;
#pragma unroll
    for (int e = 0; e < 8; ++e) u.h[e] = (_Float16)src[e];
    *(short8*)(Wp + (size_t)fid * 8) = u.s;
}

// ---- h0 -> fp16 fragment layout in buffer 0; zero flags + counters ----
// unit U=(k>>5)*8+((k>>2)&7); u64 idx = U*256 + M  (boff == M)
// cnt layout (u32): [0..255] = flags[gm*32+jt2] (0 => h_0 ready);
//                   [256+gm*8+{0,1,2}] = {safe barrier, xcd mask, arrive}
__global__ __launch_bounds__(256) void prep_state(const float* __restrict__ h0,
                                                  unsigned long long* __restrict__ hb0,
                                                  unsigned int* __restrict__ cnt) {
    int gid = blockIdx.x * 256 + threadIdx.x;   // 0..65535
    int r = gid & 255;
    int U = gid >> 8;
    int kb = (U >> 3) * 32 + ((U >> 1) & 3) * 8 + (U & 1) * 4;
    float4 v = *(const float4*)(h0 + (size_t)r * HH + kb);
    union { _Float16 h[4]; unsigned long long u; } x;
    x.h[0] = (_Float16)v.x; x.h[1] = (_Float16)v.y;
    x.h[2] = (_Float16)v.z; x.h[3] = (_Float16)v.w;
    hb0[(size_t)U * 256 + r] = x.u;
    if (blockIdx.x == 0) {
        cnt[threadIdx.x] = 0;          // flags
        cnt[256 + threadIdx.x] = 0;    // counters region
    }
}

// ---- persistent LSTM kernel: all 512 steps + final FC ----
__global__ __launch_bounds__(512, 1) void lstm_persist(
    const float* __restrict__ y_hist,
    const float* __restrict__ W_ih,           // (4096) flat
    const float* __restrict__ b_ih,
    const float* __restrict__ b_hh,
    const float* __restrict__ c0,             // (B,H) f32
    const float* __restrict__ W_fc,           // (H)
    const float* __restrict__ b_fc,           // (1)
    const unsigned short* __restrict__ Wp,    // packed fp16 W fragments
    unsigned long long* hbase,                // 2 buffers x HP_U64 u64
    unsigned int* cnt,
    float* __restrict__ out)
{
    __shared__ __align__(16) unsigned short Wlds[65536];   // 128 KB: gates 0,1
    __shared__ __align__(16) float scr[8192];              // 32 KB: 4 regions x 2048
    // 160 KiB exactly -> 1 WG/CU; grid=256 => all WGs co-resident

    const int tid = threadIdx.x;
    const int lane = tid & 63;
    const int wv = tid >> 6;
    const int m2 = wv & 1;                     // m half (16 rows)
    const int k4 = wv >> 1;                    // K quarter (256 k)
    const int bid = blockIdx.x;
    const int gm = bid & 7;                    // m-group == XCD id (round-robin)
    const int jt2 = bid >> 3;                  // 32-j tile

    const unsigned short* WpJ = Wp + (size_t)jt2 * 131072;

    // --- LDS: gates 0,1 fragments (all kc) ---
    for (int f = tid; f < 8192; f += 512) {
        int kc = f >> 8, g = (f >> 7) & 1, low = f & 127;
        *(short8*)&Wlds[(size_t)((kc * 2 + g) * 128 + low) * 8] =
            *(const short8*)(WpJ + (size_t)((kc * 4 + g) * 128 + low) * 8);
    }
    // --- registers: gates 2,3 fragments for this wave's K-quarter ---
    half8 Breg[8][2][2];   // [kc_l][g-2][nt]
#pragma unroll
    for (int kc_l = 0; kc_l < 8; ++kc_l) {
        int kc = k4 * 8 + kc_l;
#pragma unroll
        for (int g2 = 0; g2 < 2; ++g2)
#pragma unroll
            for (int nt = 0; nt < 2; ++nt)
                Breg[kc_l][g2][nt] = *(const half8*)
                    (WpJ + (size_t)((((kc * 4 + 2 + g2) * 2 + nt) * 64 + lane)) * 8);
    }

    // --- A addressing ---
    const int blk = gm * 2 + m2;               // 16-row block 0..15
    const int q = lane >> 4;
    const size_t abase = (size_t)blk * 16 + (lane & 15);
    const size_t qoff = (size_t)q * 512;

    // --- epilogue constants (ALL 512 threads: cell = 1 row x 2 j) ---
    const int em = tid & 31;                   // tile-local row
    const int jp = tid >> 5;                   // j-pair 0..15
    const int jq = jp >> 1;
    const int M = gm * 32 + em;
    float wi_[4][2], bs_[4][2], c_[2];
#pragma unroll
    for (int g = 0; g < 4; ++g)
#pragma unroll
        for (int jj = 0; jj < 2; ++jj) {
            int j = jt2 * 32 + jp * 2 + jj;
            wi_[g][jj] = W_ih[g * HH + j];
            bs_[g][jj] = b_ih[g * HH + j] + b_hh[g * HH + j];
        }
#pragma unroll
    for (int jj = 0; jj < 2; ++jj)
        c_[jj] = c0[(size_t)M * HH + jt2 * 32 + jp * 2 + jj];
    // u32 store index: ((jt2*8+jq)*256 + M)*2 + (jp&1); wave = full 256B line
    const size_t sidx32 = ((size_t)(jt2 * 8 + jq) * 256 + M) * 2 + (jp & 1);

    __syncthreads();   // Wlds visible

    unsigned int* flags = cnt + gm * 32;              // 32 flags, one per jt2
    unsigned int* grp = cnt + 256 + gm * 8;           // [0]=bar [1]=mask [2]=arrive
    const int ml = q * 4;                      // local row base within 16-row tile

    // --- spin budget: hang-proofing (v10.3-proven) ---
    unsigned spin_budget = 1u << 20;

    // --- XCD-uniformity detection (device-scope, once). Bailout -> SAFE. ---
    if (tid == 0) {
        unsigned myxcd;
        asm volatile("s_getreg_b32 %0, hwreg(HW_REG_XCC_ID)" : "=s"(myxcd));
        __hip_atomic_fetch_or(grp + 1, 1u << (myxcd & 31u),
                              __ATOMIC_RELAXED, __HIP_MEMORY_SCOPE_AGENT);
        __hip_atomic_fetch_add(grp + 2, 1u,
                               __ATOMIC_RELAXED, __HIP_MEMORY_SCOPE_AGENT);
        int ok = 0;
        while (spin_budget) {
            if (__hip_atomic_load(grp + 2, __ATOMIC_RELAXED,
                                  __HIP_MEMORY_SCOPE_AGENT) >= 32u) { ok = 1; break; }
            __builtin_amdgcn_s_sleep(1);
            --spin_budget;
        }
        unsigned mm = __hip_atomic_load(grp + 1, __ATOMIC_RELAXED,
                                        __HIP_MEMORY_SCOPE_AGENT);
        ((volatile int*)scr)[0] = (ok && ((mm & (mm - 1u)) == 0u)) ? 1 : 0;
    }
    __syncthreads();
    const bool fastmode = (((volatile int*)scr)[0] != 0);
    __syncthreads();   // flag captured before scr reuse

    auto mainloop = [&](auto FASTC) {
        constexpr bool FAST = decltype(FASTC)::value;
        for (int t = 0; t < TT; ++t) {
            const unsigned long long* hR = hbase + (size_t)(t & 1) * HP_U64;
            unsigned long long* hW = hbase + (size_t)((t + 1) & 1) * HP_U64;

            // prefetch y_hist x (consumed in epilogue; hides under K-loop)
            float x = y_hist[(size_t)M * TT + t];

            float4v acc[8] = {{0.f,0.f,0.f,0.f},{0.f,0.f,0.f,0.f},{0.f,0.f,0.f,0.f},
                              {0.f,0.f,0.f,0.f},{0.f,0.f,0.f,0.f},{0.f,0.f,0.f,0.f},
                              {0.f,0.f,0.f,0.f},{0.f,0.f,0.f,0.f}};

            unsigned long long ring[8][2];
            if constexpr (FAST) {
                // --- dataflow gate: wave k4 needs ONLY producers jt2 in
                //     [8*k4, 8*k4+8) to have flag >= t (h_t visible in L2) ---
                {
                    unsigned int* fp = flags + k4 * 8 + (lane & 7);
                    const unsigned need = (unsigned)t;
                    while (spin_budget) {
                        unsigned f;
                        asm volatile("global_load_dword %0, %1, off sc1\n\t"
                                     "s_waitcnt vmcnt(0)"
                                     : "=v"(f) : "v"(fp) : "memory");
                        if (__all((int)(f >= need))) break;
                        __builtin_amdgcn_s_sleep(1);
                        --spin_budget;
                    }
                }
                // sc1 loads: device scope — probes same-XCD L2, hits dirty
                // lines from producers' sc0 stores; bypasses stale L1.
#pragma unroll
                for (int p = 0; p < 8; ++p) {
                    size_t ua = (size_t)(k4 * 8 + p) * 2048 + qoff + abase;
                    asm volatile("global_load_dwordx2 %0, %1, off sc1"
                                 : "=v"(ring[p][0]) : "v"(&hR[ua]));
                    asm volatile("global_load_dwordx2 %0, %1, off sc1"
                                 : "=v"(ring[p][1]) : "v"(&hR[ua + 256]));
                }
                asm volatile("s_waitcnt vmcnt(0)" ::: "memory");
                __builtin_amdgcn_sched_barrier(0);   // rule #18: pin uses after wait
            } else {
#pragma unroll
                for (int p = 0; p < 8; ++p) {
                    size_t ua = (size_t)(k4 * 8 + p) * 2048 + qoff + abase;
                    ring[p][0] = __hip_atomic_load((unsigned long long*)&hR[ua],
                                                   __ATOMIC_RELAXED, __HIP_MEMORY_SCOPE_AGENT);
                    ring[p][1] = __hip_atomic_load((unsigned long long*)&hR[ua + 256],
                                                   __ATOMIC_RELAXED, __HIP_MEMORY_SCOPE_AGENT);
                }
            }
#pragma unroll
            for (int ch = 0; ch < 8; ++ch) {
                union { unsigned long long u[2]; half8 h; } af;
                af.u[0] = ring[ch][0];
                af.u[1] = ring[ch][1];
                const int kc = k4 * 8 + ch;
#pragma unroll
                for (int g = 0; g < 2; ++g)
#pragma unroll
                    for (int nt = 0; nt < 2; ++nt) {
                        half8 bh = *(const half8*)
                            &Wlds[(size_t)((kc * 2 + g) * 128 + nt * 64 + lane) * 8];
                        acc[g * 2 + nt] =
                            __builtin_amdgcn_mfma_f32_16x16x32_f16(af.h, bh, acc[g * 2 + nt], 0, 0, 0);
                    }
#pragma unroll
                for (int g2 = 0; g2 < 2; ++g2)
#pragma unroll
                    for (int nt = 0; nt < 2; ++nt)
                        acc[(2 + g2) * 2 + nt] =
                            __builtin_amdgcn_mfma_f32_16x16x32_f16(af.h, Breg[ch][g2][nt],
                                                                   acc[(2 + g2) * 2 + nt], 0, 0, 0);
            }

            // --- 4-way k-reduction, 2 rounds in 32 KB scratch (v6-proven) ---
            if (k4 >= 2) {
                int rb = (m2 * 2 + (k4 & 1)) * 2048;
#pragma unroll
                for (int a = 0; a < 8; ++a) {
                    int n = (a >> 1) * 32 + (a & 1) * 16 + (lane & 15);
                    *(float4v*)&scr[rb + n * 16 + (ml ^ ((n & 3) << 2))] = acc[a];
                }
            }
            __syncthreads();
            if (k4 < 2) {
                int rb = (m2 * 2 + k4) * 2048;
#pragma unroll
                for (int a = 0; a < 8; ++a) {
                    int n = (a >> 1) * 32 + (a & 1) * 16 + (lane & 15);
                    acc[a] += *(const float4v*)&scr[rb + n * 16 + (ml ^ ((n & 3) << 2))];
                }
                if (k4 == 1) {
#pragma unroll
                    for (int a = 0; a < 8; ++a) {
                        int n = (a >> 1) * 32 + (a & 1) * 16 + (lane & 15);
                        *(float4v*)&scr[(m2 * 2 + 1) * 2048 + n * 16 + (ml ^ ((n & 3) << 2))] = acc[a];
                    }
                }
            }
            __syncthreads();
            if (k4 == 0) {
#pragma unroll
                for (int a = 0; a < 8; ++a) {
                    int n = (a >> 1) * 32 + (a & 1) * 16 + (lane & 15);
                    int sw = n * 16 + (ml ^ ((n & 3) << 2));
                    acc[a] += *(const float4v*)&scr[(m2 * 2 + 1) * 2048 + sw];
                    *(float4v*)&scr[(m2 * 2) * 2048 + sw] = acc[a];
                }
            }
            __syncthreads();

            // --- epilogue (all 512 threads): 1 row x 2 j; one u32 store ---
            {
                int rbase = (em >> 4) * 2 * 2048;
                union { _Float16 h[2]; unsigned int u; } hv;
#pragma unroll
                for (int jj = 0; jj < 2; ++jj) {
                    int jl = jp * 2 + jj;                      // 0..31
                    int msw = (em & 15) ^ ((jl & 3) << 2);
                    float gi = scr[rbase + (0 * 32 + jl) * 16 + msw] + x * wi_[0][jj] + bs_[0][jj];
                    float gf = scr[rbase + (1 * 32 + jl) * 16 + msw] + x * wi_[1][jj] + bs_[1][jj];
                    float gg = scr[rbase + (2 * 32 + jl) * 16 + msw] + x * wi_[2][jj] + bs_[2][jj];
                    float go = scr[rbase + (3 * 32 + jl) * 16 + msw] + x * wi_[3][jj] + bs_[3][jj];
                    float cn = sigf(gf) * c_[jj] + sigf(gi) * tanhff(gg);
                    float hn = sigf(go) * tanhff(cn);
                    c_[jj] = cn;
                    hv.h[jj] = (_Float16)hn;
                }
                if constexpr (FAST)
                    asm volatile("global_store_dword %0, %1, off sc0"
                                 : : "v"((void*)((unsigned int*)hW + sidx32)), "v"(hv.u) : "memory");
                else
                    asm volatile("global_store_dword %0, %1, off sc0 sc1"
                                 : : "v"((void*)((unsigned int*)hW + sidx32)), "v"(hv.u) : "memory");
            }

            // --- drain stores, join waves, publish ---
            asm volatile("s_waitcnt vmcnt(0)" ::: "memory");
            __syncthreads();
            if constexpr (FAST) {
                // plain sc0 store (no RMW chain): flag[jt2] = t+1 after ALL
                // of this WG's h stores are L2-visible (drain before join).
                if (tid == 0) {
                    unsigned v = (unsigned)(t + 1);
                    asm volatile("global_store_dword %0, %1, off sc0"
                                 : : "v"((void*)(flags + jt2)), "v"(v) : "memory");
                }
                // no trailing sync: waves gate themselves on flags next step
            } else {
                if (tid == 0) {
                    unsigned target = 32u * (unsigned)(t + 1);
                    __hip_atomic_fetch_add(grp, 1u, __ATOMIC_RELAXED,
                                           __HIP_MEMORY_SCOPE_AGENT);
                    while (spin_budget &&
                           __hip_atomic_load(grp, __ATOMIC_RELAXED,
                                             __HIP_MEMORY_SCOPE_AGENT) < target) {
                        __builtin_amdgcn_s_sleep(1);
                        --spin_budget;
                    }
                }
                __syncthreads();
            }
        }
    };
    if (fastmode) mainloop(std::integral_constant<bool, true>{});
    else          mainloop(std::integral_constant<bool, false>{});

    // --- final FC (h final in buffer 0): jt2==0 WGs, k4==0 waves ---
    if (jt2 == 0 && k4 == 0) {
        if (fastmode) {
            // wait for ALL 32 producers' final stores (flag >= 512)
            unsigned int* fb = flags + (lane & 31);
            while (spin_budget) {
                unsigned f;
                asm volatile("global_load_dword %0, %1, off sc1\n\t"
                             "s_waitcnt vmcnt(0)"
                             : "=v"(f) : "v"(fb) : "memory");
                if (__all((int)(f >= (unsigned)TT))) break;
                __builtin_amdgcn_s_sleep(1);
                --spin_budget;
            }
        }
        const unsigned long long* hF = hbase;   // buffer 0
#pragma unroll 1
        for (int rr = 0; rr < 16; ++rr) {
            int row = gm * 32 + m2 * 16 + rr;
            int boff = row;                     // boff == M
            float s = 0.f;
#pragma unroll 1
            for (int uu = 0; uu < 4; ++uu) {
                int U = uu * 64 + lane;
                unsigned long long u;
                if (fastmode) {
                    asm volatile("global_load_dwordx2 %0, %1, off sc1\n\ts_waitcnt vmcnt(0)"
                                 : "=v"(u) : "v"(&hF[(size_t)U * 256 + boff]) : "memory");
                } else {
                    u = __hip_atomic_load((unsigned long long*)&hF[(size_t)U * 256 + boff],
                                          __ATOMIC_RELAXED, __HIP_MEMORY_SCOPE_AGENT);
                }
                int kb = (U >> 3) * 32 + ((U >> 1) & 3) * 8 + (U & 1) * 4;
                union { _Float16 h[4]; unsigned long long x; } v;
                v.x = u;
                float4 wf = *(const float4*)(W_fc + kb);
                s += (float)v.h[0] * wf.x + (float)v.h[1] * wf.y +
                     (float)v.h[2] * wf.z + (float)v.h[3] * wf.w;
            }
#pragma unroll
            for (int off = 32; off > 0; off >>= 1) s += __shfl_xor(s, off);
            if (lane == 0) out[row] = s + b_fc[0];
        }
    }
}

extern "C" void kernel_launch(void* const* d_in, const int* in_sizes, int n_in,
                              void* d_out, int out_size, void* d_ws, size_t ws_size,
                              hipStream_t stream) {
    const float* y_hist = (const float*)d_in[0];
    const float* W_ih   = (const float*)d_in[1];
    const float* W_hh   = (const float*)d_in[2];
    const float* b_ih   = (const float*)d_in[3];
    const float* b_hh   = (const float*)d_in[4];
    const float* W_fc   = (const float*)d_in[5];
    const float* b_fc   = (const float*)d_in[6];
    const float* h0     = (const float*)d_in[7];
    const float* c0     = (const float*)d_in[8];
    float* out = (float*)d_out;

    // ws: Wp fp16 (8 MB) | h buffers 2 x 512 KB | cnt (2 KB)
    unsigned short* Wp = (unsigned short*)d_ws;
    unsigned long long* hbase = (unsigned long long*)(Wp + (size_t)4194304);
    unsigned int* cnt = (unsigned int*)(hbase + 2 * HP_U64);

    pack_w<<<2048, 256, 0, stream>>>(W_hh, Wp);
    prep_state<<<256, 256, 0, stream>>>(h0, hbase, cnt);

    // 256 WGs x 512 threads, 160 KiB LDS -> 1 WG/CU, all co-resident
    lstm_persist<<<256, 512, 0, stream>>>(y_hist, W_ih, b_ih, b_hh, c0, W_fc, b_fc,
                                          Wp, hbase, cnt, out);
}

// Round 13
// 1937.573 us; speedup vs baseline: 1.5627x; 1.0881x over previous
//
#include <hip/hip_runtime.h>
#include <hip/hip_bf16.h>
#include <type_traits>

// LSTM decoder B=256, T=512, H=1024 — persistent fp16 MFMA, v16.
// Base = v15 (2108 us measured WIN: dataflow flags replaced the monolithic
// barrier; WRITE 1MB, MfmaUtil 20.9). Two latency-chain cuts:
//  1) FAST K-loop ring: asm sc1 loads + vmcnt(0) full drain + sched_barrier
//     -> __hip_atomic_load (AGENT) like the safe path. Compiler then emits
//     counted per-chunk vmcnt and pipelines ds_reads across chunks (the
//     asm drain blocked both). Agent atomic loads bypass stale L1 (proven:
//     v8 passed with 2-step address reuse). Gate's "memory"-clobber asm
//     still orders ring after flags. Gate poll: s_sleep removed (64-cy
//     quantization), spin budget kept -> still hang-proof.
//  2) Reduction rounds 1-2 remapped to lane-contiguous float4 (canonical
//     conflict-free; v9 evidence: 10x conflict drop). SQ_LDS_BANK_CONFLICT
//     = 1.091e8 constant across v8..v15 INCLUDING no-Wlds v14 -> conflicts
//     are entirely in scr reduction (~833 cy/CU/step). Final swizzled
//     write + epilogue read unchanged.
// Everything else byte-identical to v15.

#define BB 256
#define TT 512
#define HH 1024

typedef __attribute__((ext_vector_type(8))) short short8;
typedef __attribute__((ext_vector_type(8))) _Float16 half8;
typedef __attribute__((ext_vector_type(4))) float float4v;

#define HP_U64 ((size_t)65536)   // u64 per h buffer: 256 U-units x 256 rows

__device__ __forceinline__ float sigf(float x) { return 1.0f / (1.0f + __expf(-x)); }
__device__ __forceinline__ float tanhff(float x) {
    return 1.0f - 2.0f / (__expf(2.0f * x) + 1.0f);
}

// ---- pack W_hh (4096x1024 f32) -> fp16 B-fragment order ----
// Wp[jt2(32)][kc(32)][g(4)][nt(2)][lane(64)][8] ; per-jt2 block = 256 KB
__global__ __launch_bounds__(256) void pack_w(const float* __restrict__ W_hh,
                                              unsigned short* __restrict__ Wp) {
    int fid = blockIdx.x * 256 + threadIdx.x;   // 0..524287
    int lane = fid & 63;
    int nt = (fid >> 6) & 1;
    int g = (fid >> 7) & 3;
    int kc = (fid >> 9) & 31;
    int jt2 = fid >> 14;
    int j = jt2 * 32 + nt * 16 + (lane & 15);
    int row = g * HH + j;
    int k = kc * 32 + (lane >> 4) * 8;
    const float* src = W_hh + (size_t)row * HH + k;
    union { _Float16 h[8]; short8 s; } u;
#pragma unroll
    for (int e = 0; e < 8; ++e) u.h[e] = (_Float16)src[e];
    *(short8*)(Wp + (size_t)fid * 8) = u.s;
}

// ---- h0 -> fp16 fragment layout in buffer 0; zero flags + counters ----
// unit U=(k>>5)*8+((k>>2)&7); u64 idx = U*256 + M  (boff == M)
// cnt layout (u32): [0..255] = flags[gm*32+jt2] (0 => h_0 ready);
//                   [256+gm*8+{0,1,2}] = {safe barrier, xcd mask, arrive}
__global__ __launch_bounds__(256) void prep_state(const float* __restrict__ h0,
                                                  unsigned long long* __restrict__ hb0,
                                                  unsigned int* __restrict__ cnt) {
    int gid = blockIdx.x * 256 + threadIdx.x;   // 0..65535
    int r = gid & 255;
    int U = gid >> 8;
    int kb = (U >> 3) * 32 + ((U >> 1) & 3) * 8 + (U & 1) * 4;
    float4 v = *(const float4*)(h0 + (size_t)r * HH + kb);
    union { _Float16 h[4]; unsigned long long u; } x;
    x.h[0] = (_Float16)v.x; x.h[1] = (_Float16)v.y;
    x.h[2] = (_Float16)v.z; x.h[3] = (_Float16)v.w;
    hb0[(size_t)U * 256 + r] = x.u;
    if (blockIdx.x == 0) {
        cnt[threadIdx.x] = 0;          // flags
        cnt[256 + threadIdx.x] = 0;    // counters region
    }
}

// ---- persistent LSTM kernel: all 512 steps + final FC ----
__global__ __launch_bounds__(512, 1) void lstm_persist(
    const float* __restrict__ y_hist,
    const float* __restrict__ W_ih,           // (4096) flat
    const float* __restrict__ b_ih,
    const float* __restrict__ b_hh,
    const float* __restrict__ c0,             // (B,H) f32
    const float* __restrict__ W_fc,           // (H)
    const float* __restrict__ b_fc,           // (1)
    const unsigned short* __restrict__ Wp,    // packed fp16 W fragments
    unsigned long long* hbase,                // 2 buffers x HP_U64 u64
    unsigned int* cnt,
    float* __restrict__ out)
{
    __shared__ __align__(16) unsigned short Wlds[65536];   // 128 KB: gates 0,1
    __shared__ __align__(16) float scr[8192];              // 32 KB: 4 slots x 2048
    // 160 KiB exactly -> 1 WG/CU; grid=256 => all WGs co-resident

    const int tid = threadIdx.x;
    const int lane = tid & 63;
    const int wv = tid >> 6;
    const int m2 = wv & 1;                     // m half (16 rows)
    const int k4 = wv >> 1;                    // K quarter (256 k)
    const int bid = blockIdx.x;
    const int gm = bid & 7;                    // m-group == XCD id (round-robin)
    const int jt2 = bid >> 3;                  // 32-j tile

    const unsigned short* WpJ = Wp + (size_t)jt2 * 131072;

    // --- LDS: gates 0,1 fragments (all kc) ---
    for (int f = tid; f < 8192; f += 512) {
        int kc = f >> 8, g = (f >> 7) & 1, low = f & 127;
        *(short8*)&Wlds[(size_t)((kc * 2 + g) * 128 + low) * 8] =
            *(const short8*)(WpJ + (size_t)((kc * 4 + g) * 128 + low) * 8);
    }
    // --- registers: gates 2,3 fragments for this wave's K-quarter ---
    half8 Breg[8][2][2];   // [kc_l][g-2][nt]
#pragma unroll
    for (int kc_l = 0; kc_l < 8; ++kc_l) {
        int kc = k4 * 8 + kc_l;
#pragma unroll
        for (int g2 = 0; g2 < 2; ++g2)
#pragma unroll
            for (int nt = 0; nt < 2; ++nt)
                Breg[kc_l][g2][nt] = *(const half8*)
                    (WpJ + (size_t)((((kc * 4 + 2 + g2) * 2 + nt) * 64 + lane)) * 8);
    }

    // --- A addressing ---
    const int blk = gm * 2 + m2;               // 16-row block 0..15
    const int q = lane >> 4;
    const size_t abase = (size_t)blk * 16 + (lane & 15);
    const size_t qoff = (size_t)q * 512;

    // --- epilogue constants (ALL 512 threads: cell = 1 row x 2 j) ---
    const int em = tid & 31;                   // tile-local row
    const int jp = tid >> 5;                   // j-pair 0..15
    const int jq = jp >> 1;
    const int M = gm * 32 + em;
    float wi_[4][2], bs_[4][2], c_[2];
#pragma unroll
    for (int g = 0; g < 4; ++g)
#pragma unroll
        for (int jj = 0; jj < 2; ++jj) {
            int j = jt2 * 32 + jp * 2 + jj;
            wi_[g][jj] = W_ih[g * HH + j];
            bs_[g][jj] = b_ih[g * HH + j] + b_hh[g * HH + j];
        }
#pragma unroll
    for (int jj = 0; jj < 2; ++jj)
        c_[jj] = c0[(size_t)M * HH + jt2 * 32 + jp * 2 + jj];
    // u32 store index: ((jt2*8+jq)*256 + M)*2 + (jp&1); wave = full 256B line
    const size_t sidx32 = ((size_t)(jt2 * 8 + jq) * 256 + M) * 2 + (jp & 1);

    __syncthreads();   // Wlds visible

    unsigned int* flags = cnt + gm * 32;              // 32 flags, one per jt2
    unsigned int* grp = cnt + 256 + gm * 8;           // [0]=bar [1]=mask [2]=arrive
    const int ml = q * 4;                      // local row base within 16-row tile

    // --- spin budget: hang-proofing (v10.3-proven) ---
    unsigned spin_budget = 1u << 20;

    // --- XCD-uniformity detection (device-scope, once). Bailout -> SAFE. ---
    if (tid == 0) {
        unsigned myxcd;
        asm volatile("s_getreg_b32 %0, hwreg(HW_REG_XCC_ID)" : "=s"(myxcd));
        __hip_atomic_fetch_or(grp + 1, 1u << (myxcd & 31u),
                              __ATOMIC_RELAXED, __HIP_MEMORY_SCOPE_AGENT);
        __hip_atomic_fetch_add(grp + 2, 1u,
                               __ATOMIC_RELAXED, __HIP_MEMORY_SCOPE_AGENT);
        int ok = 0;
        while (spin_budget) {
            if (__hip_atomic_load(grp + 2, __ATOMIC_RELAXED,
                                  __HIP_MEMORY_SCOPE_AGENT) >= 32u) { ok = 1; break; }
            __builtin_amdgcn_s_sleep(1);
            --spin_budget;
        }
        unsigned mm = __hip_atomic_load(grp + 1, __ATOMIC_RELAXED,
                                        __HIP_MEMORY_SCOPE_AGENT);
        ((volatile int*)scr)[0] = (ok && ((mm & (mm - 1u)) == 0u)) ? 1 : 0;
    }
    __syncthreads();
    const bool fastmode = (((volatile int*)scr)[0] != 0);
    __syncthreads();   // flag captured before scr reuse

    auto mainloop = [&](auto FASTC) {
        constexpr bool FAST = decltype(FASTC)::value;
        for (int t = 0; t < TT; ++t) {
            const unsigned long long* hR = hbase + (size_t)(t & 1) * HP_U64;
            unsigned long long* hW = hbase + (size_t)((t + 1) & 1) * HP_U64;

            // prefetch y_hist x (consumed in epilogue; hides under K-loop)
            float x = y_hist[(size_t)M * TT + t];

            float4v acc[8] = {{0.f,0.f,0.f,0.f},{0.f,0.f,0.f,0.f},{0.f,0.f,0.f,0.f},
                              {0.f,0.f,0.f,0.f},{0.f,0.f,0.f,0.f},{0.f,0.f,0.f,0.f},
                              {0.f,0.f,0.f,0.f},{0.f,0.f,0.f,0.f}};

            if constexpr (FAST) {
                // --- dataflow gate: wave k4 needs ONLY producers jt2 in
                //     [8*k4, 8*k4+8) at flag >= t. Sleepless poll (budgeted);
                //     "memory" clobber orders the ring loads after the gate. ---
                unsigned int* fp = flags + k4 * 8 + (lane & 7);
                const unsigned need = (unsigned)t;
                while (spin_budget) {
                    unsigned f;
                    asm volatile("global_load_dword %0, %1, off sc1\n\t"
                                 "s_waitcnt vmcnt(0)"
                                 : "=v"(f) : "v"(fp) : "memory");
                    if (__all((int)(f >= need))) break;
                    --spin_budget;
                }
            }
            // --- ring loads: agent atomic loads in BOTH modes. Compiler sees
            //     them -> counted per-chunk vmcnt + ds_read pipelining (the
            //     old asm+vmcnt(0) drain blocked both). Agent loads bypass
            //     stale L1 (v8-proven under 2-step address reuse). ---
            unsigned long long ring[8][2];
#pragma unroll
            for (int p = 0; p < 8; ++p) {
                size_t ua = (size_t)(k4 * 8 + p) * 2048 + qoff + abase;
                ring[p][0] = __hip_atomic_load((unsigned long long*)&hR[ua],
                                               __ATOMIC_RELAXED, __HIP_MEMORY_SCOPE_AGENT);
                ring[p][1] = __hip_atomic_load((unsigned long long*)&hR[ua + 256],
                                               __ATOMIC_RELAXED, __HIP_MEMORY_SCOPE_AGENT);
            }
#pragma unroll
            for (int ch = 0; ch < 8; ++ch) {
                union { unsigned long long u[2]; half8 h; } af;
                af.u[0] = ring[ch][0];
                af.u[1] = ring[ch][1];
                const int kc = k4 * 8 + ch;
#pragma unroll
                for (int g = 0; g < 2; ++g)
#pragma unroll
                    for (int nt = 0; nt < 2; ++nt) {
                        half8 bh = *(const half8*)
                            &Wlds[(size_t)((kc * 2 + g) * 128 + nt * 64 + lane) * 8];
                        acc[g * 2 + nt] =
                            __builtin_amdgcn_mfma_f32_16x16x32_f16(af.h, bh, acc[g * 2 + nt], 0, 0, 0);
                    }
#pragma unroll
                for (int g2 = 0; g2 < 2; ++g2)
#pragma unroll
                    for (int nt = 0; nt < 2; ++nt)
                        acc[(2 + g2) * 2 + nt] =
                            __builtin_amdgcn_mfma_f32_16x16x32_f16(af.h, Breg[ch][g2][nt],
                                                                   acc[(2 + g2) * 2 + nt], 0, 0, 0);
            }

            // --- 4-way k-reduction: rounds 1-2 lane-contiguous (conflict-free,
            //     v9-proven pattern); final write + epilogue keep the swizzle. ---
            if (k4 >= 2) {
                int sb = (m2 * 2 + (k4 & 1)) * 2048;
#pragma unroll
                for (int a = 0; a < 8; ++a)
                    *(float4v*)&scr[sb + a * 256 + lane * 4] = acc[a];
            }
            __syncthreads();
            if (k4 < 2) {
                int sb = (m2 * 2 + k4) * 2048;
#pragma unroll
                for (int a = 0; a < 8; ++a)
                    acc[a] += *(const float4v*)&scr[sb + a * 256 + lane * 4];
                if (k4 == 1) {
#pragma unroll
                    for (int a = 0; a < 8; ++a)
                        *(float4v*)&scr[sb + a * 256 + lane * 4] = acc[a];  // in place
                }
            }
            __syncthreads();
            if (k4 == 0) {
#pragma unroll
                for (int a = 0; a < 8; ++a) {
                    acc[a] += *(const float4v*)&scr[(m2 * 2 + 1) * 2048 + a * 256 + lane * 4];
                    int n = (a >> 1) * 32 + (a & 1) * 16 + (lane & 15);
                    int sw = n * 16 + (ml ^ ((n & 3) << 2));
                    *(float4v*)&scr[(m2 * 2) * 2048 + sw] = acc[a];
                }
            }
            __syncthreads();

            // --- epilogue (all 512 threads): 1 row x 2 j; one u32 store ---
            {
                int rbase = (em >> 4) * 2 * 2048;
                union { _Float16 h[2]; unsigned int u; } hv;
#pragma unroll
                for (int jj = 0; jj < 2; ++jj) {
                    int jl = jp * 2 + jj;                      // 0..31
                    int msw = (em & 15) ^ ((jl & 3) << 2);
                    float gi = scr[rbase + (0 * 32 + jl) * 16 + msw] + x * wi_[0][jj] + bs_[0][jj];
                    float gf = scr[rbase + (1 * 32 + jl) * 16 + msw] + x * wi_[1][jj] + bs_[1][jj];
                    float gg = scr[rbase + (2 * 32 + jl) * 16 + msw] + x * wi_[2][jj] + bs_[2][jj];
                    float go = scr[rbase + (3 * 32 + jl) * 16 + msw] + x * wi_[3][jj] + bs_[3][jj];
                    float cn = sigf(gf) * c_[jj] + sigf(gi) * tanhff(gg);
                    float hn = sigf(go) * tanhff(cn);
                    c_[jj] = cn;
                    hv.h[jj] = (_Float16)hn;
                }
                if constexpr (FAST)
                    asm volatile("global_store_dword %0, %1, off sc0"
                                 : : "v"((void*)((unsigned int*)hW + sidx32)), "v"(hv.u) : "memory");
                else
                    asm volatile("global_store_dword %0, %1, off sc0 sc1"
                                 : : "v"((void*)((unsigned int*)hW + sidx32)), "v"(hv.u) : "memory");
            }

            // --- drain stores, join waves, publish ---
            asm volatile("s_waitcnt vmcnt(0)" ::: "memory");
            __syncthreads();
            if constexpr (FAST) {
                // plain sc0 store (no RMW chain): flag[jt2] = t+1 after ALL
                // of this WG's h stores are L2-visible (drain before join).
                if (tid == 0) {
                    unsigned v = (unsigned)(t + 1);
                    asm volatile("global_store_dword %0, %1, off sc0"
                                 : : "v"((void*)(flags + jt2)), "v"(v) : "memory");
                }
                // no trailing sync: waves gate themselves on flags next step
            } else {
                if (tid == 0) {
                    unsigned target = 32u * (unsigned)(t + 1);
                    __hip_atomic_fetch_add(grp, 1u, __ATOMIC_RELAXED,
                                           __HIP_MEMORY_SCOPE_AGENT);
                    while (spin_budget &&
                           __hip_atomic_load(grp, __ATOMIC_RELAXED,
                                             __HIP_MEMORY_SCOPE_AGENT) < target) {
                        __builtin_amdgcn_s_sleep(1);
                        --spin_budget;
                    }
                }
                __syncthreads();
            }
        }
    };
    if (fastmode) mainloop(std::integral_constant<bool, true>{});
    else          mainloop(std::integral_constant<bool, false>{});

    // --- final FC (h final in buffer 0): jt2==0 WGs, k4==0 waves ---
    if (jt2 == 0 && k4 == 0) {
        if (fastmode) {
            // wait for ALL 32 producers' final stores (flag >= 512)
            unsigned int* fb = flags + (lane & 31);
            while (spin_budget) {
                unsigned f;
                asm volatile("global_load_dword %0, %1, off sc1\n\t"
                             "s_waitcnt vmcnt(0)"
                             : "=v"(f) : "v"(fb) : "memory");
                if (__all((int)(f >= (unsigned)TT))) break;
                __builtin_amdgcn_s_sleep(1);
                --spin_budget;
            }
        }
        const unsigned long long* hF = hbase;   // buffer 0
#pragma unroll 1
        for (int rr = 0; rr < 16; ++rr) {
            int row = gm * 32 + m2 * 16 + rr;
            int boff = row;                     // boff == M
            float s = 0.f;
#pragma unroll 1
            for (int uu = 0; uu < 4; ++uu) {
                int U = uu * 64 + lane;
                unsigned long long u;
                if (fastmode) {
                    asm volatile("global_load_dwordx2 %0, %1, off sc1\n\ts_waitcnt vmcnt(0)"
                                 : "=v"(u) : "v"(&hF[(size_t)U * 256 + boff]) : "memory");
                } else {
                    u = __hip_atomic_load((unsigned long long*)&hF[(size_t)U * 256 + boff],
                                          __ATOMIC_RELAXED, __HIP_MEMORY_SCOPE_AGENT);
                }
                int kb = (U >> 3) * 32 + ((U >> 1) & 3) * 8 + (U & 1) * 4;
                union { _Float16 h[4]; unsigned long long x; } v;
                v.x = u;
                float4 wf = *(const float4*)(W_fc + kb);
                s += (float)v.h[0] * wf.x + (float)v.h[1] * wf.y +
                     (float)v.h[2] * wf.z + (float)v.h[3] * wf.w;
            }
#pragma unroll
            for (int off = 32; off > 0; off >>= 1) s += __shfl_xor(s, off);
            if (lane == 0) out[row] = s + b_fc[0];
        }
    }
}

extern "C" void kernel_launch(void* const* d_in, const int* in_sizes, int n_in,
                              void* d_out, int out_size, void* d_ws, size_t ws_size,
                              hipStream_t stream) {
    const float* y_hist = (const float*)d_in[0];
    const float* W_ih   = (const float*)d_in[1];
    const float* W_hh   = (const float*)d_in[2];
    const float* b_ih   = (const float*)d_in[3];
    const float* b_hh   = (const float*)d_in[4];
    const float* W_fc   = (const float*)d_in[5];
    const float* b_fc   = (const float*)d_in[6];
    const float* h0     = (const float*)d_in[7];
    const float* c0     = (const float*)d_in[8];
    float* out = (float*)d_out;

    // ws: Wp fp16 (8 MB) | h buffers 2 x 512 KB | cnt (2 KB)
    unsigned short* Wp = (unsigned short*)d_ws;
    unsigned long long* hbase = (unsigned long long*)(Wp + (size_t)4194304);
    unsigned int* cnt = (unsigned int*)(hbase + 2 * HP_U64);

    pack_w<<<2048, 256, 0, stream>>>(W_hh, Wp);
    prep_state<<<256, 256, 0, stream>>>(h0, hbase, cnt);

    // 256 WGs x 512 threads, 160 KiB LDS -> 1 WG/CU, all co-resident
    lstm_persist<<<256, 512, 0, stream>>>(y_hist, W_ih, b_ih, b_hh, c0, W_fc, b_fc,
                                          Wp, hbase, cnt, out);
}

// Round 14
// 1863.892 us; speedup vs baseline: 1.6244x; 1.0395x over previous
//
#include <hip/hip_runtime.h>
#include <hip/hip_bf16.h>
#include <type_traits>

// LSTM decoder B=256, T=512, H=1024 — persistent fp16 MFMA, v17.
// Base = v16 (1937.6 us WIN: counted vmcnt + conflict-free reduce rounds;
// conflicts 1.09e8->3.36e7, MfmaUtil 22.9). ONE change:
//  x (y_hist) rotated one step ahead. v16 issued the scattered y_hist load
//  BEFORE the gate poll; the poll's vmcnt(0) then waited ~200-300cy for it
//  on the first iteration of EVERY step — pure serial-path latency. v17
//  prefetches x_{t+1} after the ring loads (hidden under MFMA, drained by
//  the epilogue vmcnt(0)), so the gate poll has no unrelated VMEM pending.
// Remaining budget model (~9.8k cy/step): Wlds port ~2-3k (structural:
// m2-pair B duplication; removing it costs occupancy, v14), MFMA ~1.2k,
// L2 h-reads ~0.5-1.1k, reduction+syncs ~0.8k, signaling ~0.6k. Rewrites
// that cut Wlds inflate reduction traffic by the same order — near a
// bandwidth-balance point.

#define BB 256
#define TT 512
#define HH 1024

typedef __attribute__((ext_vector_type(8))) short short8;
typedef __attribute__((ext_vector_type(8))) _Float16 half8;
typedef __attribute__((ext_vector_type(4))) float float4v;

#define HP_U64 ((size_t)65536)   // u64 per h buffer: 256 U-units x 256 rows

__device__ __forceinline__ float sigf(float x) { return 1.0f / (1.0f + __expf(-x)); }
__device__ __forceinline__ float tanhff(float x) {
    return 1.0f - 2.0f / (__expf(2.0f * x) + 1.0f);
}

// ---- pack W_hh (4096x1024 f32) -> fp16 B-fragment order ----
// Wp[jt2(32)][kc(32)][g(4)][nt(2)][lane(64)][8] ; per-jt2 block = 256 KB
__global__ __launch_bounds__(256) void pack_w(const float* __restrict__ W_hh,
                                              unsigned short* __restrict__ Wp) {
    int fid = blockIdx.x * 256 + threadIdx.x;   // 0..524287
    int lane = fid & 63;
    int nt = (fid >> 6) & 1;
    int g = (fid >> 7) & 3;
    int kc = (fid >> 9) & 31;
    int jt2 = fid >> 14;
    int j = jt2 * 32 + nt * 16 + (lane & 15);
    int row = g * HH + j;
    int k = kc * 32 + (lane >> 4) * 8;
    const float* src = W_hh + (size_t)row * HH + k;
    union { _Float16 h[8]; short8 s; } u;
#pragma unroll
    for (int e = 0; e < 8; ++e) u.h[e] = (_Float16)src[e];
    *(short8*)(Wp + (size_t)fid * 8) = u.s;
}

// ---- h0 -> fp16 fragment layout in buffer 0; zero flags + counters ----
// unit U=(k>>5)*8+((k>>2)&7); u64 idx = U*256 + M  (boff == M)
// cnt layout (u32): [0..255] = flags[gm*32+jt2] (0 => h_0 ready);
//                   [256+gm*8+{0,1,2}] = {safe barrier, xcd mask, arrive}
__global__ __launch_bounds__(256) void prep_state(const float* __restrict__ h0,
                                                  unsigned long long* __restrict__ hb0,
                                                  unsigned int* __restrict__ cnt) {
    int gid = blockIdx.x * 256 + threadIdx.x;   // 0..65535
    int r = gid & 255;
    int U = gid >> 8;
    int kb = (U >> 3) * 32 + ((U >> 1) & 3) * 8 + (U & 1) * 4;
    float4 v = *(const float4*)(h0 + (size_t)r * HH + kb);
    union { _Float16 h[4]; unsigned long long u; } x;
    x.h[0] = (_Float16)v.x; x.h[1] = (_Float16)v.y;
    x.h[2] = (_Float16)v.z; x.h[3] = (_Float16)v.w;
    hb0[(size_t)U * 256 + r] = x.u;
    if (blockIdx.x == 0) {
        cnt[threadIdx.x] = 0;          // flags
        cnt[256 + threadIdx.x] = 0;    // counters region
    }
}

// ---- persistent LSTM kernel: all 512 steps + final FC ----
__global__ __launch_bounds__(512, 1) void lstm_persist(
    const float* __restrict__ y_hist,
    const float* __restrict__ W_ih,           // (4096) flat
    const float* __restrict__ b_ih,
    const float* __restrict__ b_hh,
    const float* __restrict__ c0,             // (B,H) f32
    const float* __restrict__ W_fc,           // (H)
    const float* __restrict__ b_fc,           // (1)
    const unsigned short* __restrict__ Wp,    // packed fp16 W fragments
    unsigned long long* hbase,                // 2 buffers x HP_U64 u64
    unsigned int* cnt,
    float* __restrict__ out)
{
    __shared__ __align__(16) unsigned short Wlds[65536];   // 128 KB: gates 0,1
    __shared__ __align__(16) float scr[8192];              // 32 KB: 4 slots x 2048
    // 160 KiB exactly -> 1 WG/CU; grid=256 => all WGs co-resident

    const int tid = threadIdx.x;
    const int lane = tid & 63;
    const int wv = tid >> 6;
    const int m2 = wv & 1;                     // m half (16 rows)
    const int k4 = wv >> 1;                    // K quarter (256 k)
    const int bid = blockIdx.x;
    const int gm = bid & 7;                    // m-group == XCD id (round-robin)
    const int jt2 = bid >> 3;                  // 32-j tile

    const unsigned short* WpJ = Wp + (size_t)jt2 * 131072;

    // --- LDS: gates 0,1 fragments (all kc) ---
    for (int f = tid; f < 8192; f += 512) {
        int kc = f >> 8, g = (f >> 7) & 1, low = f & 127;
        *(short8*)&Wlds[(size_t)((kc * 2 + g) * 128 + low) * 8] =
            *(const short8*)(WpJ + (size_t)((kc * 4 + g) * 128 + low) * 8);
    }
    // --- registers: gates 2,3 fragments for this wave's K-quarter ---
    half8 Breg[8][2][2];   // [kc_l][g-2][nt]
#pragma unroll
    for (int kc_l = 0; kc_l < 8; ++kc_l) {
        int kc = k4 * 8 + kc_l;
#pragma unroll
        for (int g2 = 0; g2 < 2; ++g2)
#pragma unroll
            for (int nt = 0; nt < 2; ++nt)
                Breg[kc_l][g2][nt] = *(const half8*)
                    (WpJ + (size_t)((((kc * 4 + 2 + g2) * 2 + nt) * 64 + lane)) * 8);
    }

    // --- A addressing ---
    const int blk = gm * 2 + m2;               // 16-row block 0..15
    const int q = lane >> 4;
    const size_t abase = (size_t)blk * 16 + (lane & 15);
    const size_t qoff = (size_t)q * 512;

    // --- epilogue constants (ALL 512 threads: cell = 1 row x 2 j) ---
    const int em = tid & 31;                   // tile-local row
    const int jp = tid >> 5;                   // j-pair 0..15
    const int jq = jp >> 1;
    const int M = gm * 32 + em;
    float wi_[4][2], bs_[4][2], c_[2];
#pragma unroll
    for (int g = 0; g < 4; ++g)
#pragma unroll
        for (int jj = 0; jj < 2; ++jj) {
            int j = jt2 * 32 + jp * 2 + jj;
            wi_[g][jj] = W_ih[g * HH + j];
            bs_[g][jj] = b_ih[g * HH + j] + b_hh[g * HH + j];
        }
#pragma unroll
    for (int jj = 0; jj < 2; ++jj)
        c_[jj] = c0[(size_t)M * HH + jt2 * 32 + jp * 2 + jj];
    // u32 store index: ((jt2*8+jq)*256 + M)*2 + (jp&1); wave = full 256B line
    const size_t sidx32 = ((size_t)(jt2 * 8 + jq) * 256 + M) * 2 + (jp & 1);

    __syncthreads();   // Wlds visible

    unsigned int* flags = cnt + gm * 32;              // 32 flags, one per jt2
    unsigned int* grp = cnt + 256 + gm * 8;           // [0]=bar [1]=mask [2]=arrive
    const int ml = q * 4;                      // local row base within 16-row tile

    // --- spin budget: hang-proofing (v10.3-proven) ---
    unsigned spin_budget = 1u << 20;

    // --- XCD-uniformity detection (device-scope, once). Bailout -> SAFE. ---
    if (tid == 0) {
        unsigned myxcd;
        asm volatile("s_getreg_b32 %0, hwreg(HW_REG_XCC_ID)" : "=s"(myxcd));
        __hip_atomic_fetch_or(grp + 1, 1u << (myxcd & 31u),
                              __ATOMIC_RELAXED, __HIP_MEMORY_SCOPE_AGENT);
        __hip_atomic_fetch_add(grp + 2, 1u,
                               __ATOMIC_RELAXED, __HIP_MEMORY_SCOPE_AGENT);
        int ok = 0;
        while (spin_budget) {
            if (__hip_atomic_load(grp + 2, __ATOMIC_RELAXED,
                                  __HIP_MEMORY_SCOPE_AGENT) >= 32u) { ok = 1; break; }
            __builtin_amdgcn_s_sleep(1);
            --spin_budget;
        }
        unsigned mm = __hip_atomic_load(grp + 1, __ATOMIC_RELAXED,
                                        __HIP_MEMORY_SCOPE_AGENT);
        ((volatile int*)scr)[0] = (ok && ((mm & (mm - 1u)) == 0u)) ? 1 : 0;
    }
    __syncthreads();
    const bool fastmode = (((volatile int*)scr)[0] != 0);
    __syncthreads();   // flag captured before scr reuse

    auto mainloop = [&](auto FASTC) {
        constexpr bool FAST = decltype(FASTC)::value;
        // x rotated one step ahead: gate poll must see NO unrelated VMEM.
        float xcur = y_hist[(size_t)M * TT];
        for (int t = 0; t < TT; ++t) {
            const unsigned long long* hR = hbase + (size_t)(t & 1) * HP_U64;
            unsigned long long* hW = hbase + (size_t)((t + 1) & 1) * HP_U64;

            float4v acc[8] = {{0.f,0.f,0.f,0.f},{0.f,0.f,0.f,0.f},{0.f,0.f,0.f,0.f},
                              {0.f,0.f,0.f,0.f},{0.f,0.f,0.f,0.f},{0.f,0.f,0.f,0.f},
                              {0.f,0.f,0.f,0.f},{0.f,0.f,0.f,0.f}};

            if constexpr (FAST) {
                // --- dataflow gate: wave k4 needs ONLY producers jt2 in
                //     [8*k4, 8*k4+8) at flag >= t. Sleepless poll (budgeted);
                //     "memory" clobber orders the ring loads after the gate.
                //     No other VMEM outstanding -> vmcnt(0) waits poll only. ---
                unsigned int* fp = flags + k4 * 8 + (lane & 7);
                const unsigned need = (unsigned)t;
                while (spin_budget) {
                    unsigned f;
                    asm volatile("global_load_dword %0, %1, off sc1\n\t"
                                 "s_waitcnt vmcnt(0)"
                                 : "=v"(f) : "v"(fp) : "memory");
                    if (__all((int)(f >= need))) break;
                    --spin_budget;
                }
            }
            // --- ring loads: agent atomic loads in BOTH modes (counted
            //     per-chunk vmcnt + ds_read pipelining by the compiler). ---
            unsigned long long ring[8][2];
#pragma unroll
            for (int p = 0; p < 8; ++p) {
                size_t ua = (size_t)(k4 * 8 + p) * 2048 + qoff + abase;
                ring[p][0] = __hip_atomic_load((unsigned long long*)&hR[ua],
                                               __ATOMIC_RELAXED, __HIP_MEMORY_SCOPE_AGENT);
                ring[p][1] = __hip_atomic_load((unsigned long long*)&hR[ua + 256],
                                               __ATOMIC_RELAXED, __HIP_MEMORY_SCOPE_AGENT);
            }
            // prefetch next-step x here: latency hides under MFMA; drained by
            // the epilogue vmcnt(0) -> NOT pending at the next gate poll.
            float xnext = y_hist[(size_t)M * TT + (t + 1 < TT ? t + 1 : TT - 1)];
#pragma unroll
            for (int ch = 0; ch < 8; ++ch) {
                union { unsigned long long u[2]; half8 h; } af;
                af.u[0] = ring[ch][0];
                af.u[1] = ring[ch][1];
                const int kc = k4 * 8 + ch;
#pragma unroll
                for (int g = 0; g < 2; ++g)
#pragma unroll
                    for (int nt = 0; nt < 2; ++nt) {
                        half8 bh = *(const half8*)
                            &Wlds[(size_t)((kc * 2 + g) * 128 + nt * 64 + lane) * 8];
                        acc[g * 2 + nt] =
                            __builtin_amdgcn_mfma_f32_16x16x32_f16(af.h, bh, acc[g * 2 + nt], 0, 0, 0);
                    }
#pragma unroll
                for (int g2 = 0; g2 < 2; ++g2)
#pragma unroll
                    for (int nt = 0; nt < 2; ++nt)
                        acc[(2 + g2) * 2 + nt] =
                            __builtin_amdgcn_mfma_f32_16x16x32_f16(af.h, Breg[ch][g2][nt],
                                                                   acc[(2 + g2) * 2 + nt], 0, 0, 0);
            }

            // --- 4-way k-reduction: rounds 1-2 lane-contiguous (conflict-free);
            //     final write + epilogue keep the swizzle (v16-proven). ---
            if (k4 >= 2) {
                int sb = (m2 * 2 + (k4 & 1)) * 2048;
#pragma unroll
                for (int a = 0; a < 8; ++a)
                    *(float4v*)&scr[sb + a * 256 + lane * 4] = acc[a];
            }
            __syncthreads();
            if (k4 < 2) {
                int sb = (m2 * 2 + k4) * 2048;
#pragma unroll
                for (int a = 0; a < 8; ++a)
                    acc[a] += *(const float4v*)&scr[sb + a * 256 + lane * 4];
                if (k4 == 1) {
#pragma unroll
                    for (int a = 0; a < 8; ++a)
                        *(float4v*)&scr[sb + a * 256 + lane * 4] = acc[a];  // in place
                }
            }
            __syncthreads();
            if (k4 == 0) {
#pragma unroll
                for (int a = 0; a < 8; ++a) {
                    acc[a] += *(const float4v*)&scr[(m2 * 2 + 1) * 2048 + a * 256 + lane * 4];
                    int n = (a >> 1) * 32 + (a & 1) * 16 + (lane & 15);
                    int sw = n * 16 + (ml ^ ((n & 3) << 2));
                    *(float4v*)&scr[(m2 * 2) * 2048 + sw] = acc[a];
                }
            }
            __syncthreads();

            // --- epilogue (all 512 threads): 1 row x 2 j; one u32 store ---
            {
                int rbase = (em >> 4) * 2 * 2048;
                union { _Float16 h[2]; unsigned int u; } hv;
#pragma unroll
                for (int jj = 0; jj < 2; ++jj) {
                    int jl = jp * 2 + jj;                      // 0..31
                    int msw = (em & 15) ^ ((jl & 3) << 2);
                    float gi = scr[rbase + (0 * 32 + jl) * 16 + msw] + xcur * wi_[0][jj] + bs_[0][jj];
                    float gf = scr[rbase + (1 * 32 + jl) * 16 + msw] + xcur * wi_[1][jj] + bs_[1][jj];
                    float gg = scr[rbase + (2 * 32 + jl) * 16 + msw] + xcur * wi_[2][jj] + bs_[2][jj];
                    float go = scr[rbase + (3 * 32 + jl) * 16 + msw] + xcur * wi_[3][jj] + bs_[3][jj];
                    float cn = sigf(gf) * c_[jj] + sigf(gi) * tanhff(gg);
                    float hn = sigf(go) * tanhff(cn);
                    c_[jj] = cn;
                    hv.h[jj] = (_Float16)hn;
                }
                if constexpr (FAST)
                    asm volatile("global_store_dword %0, %1, off sc0"
                                 : : "v"((void*)((unsigned int*)hW + sidx32)), "v"(hv.u) : "memory");
                else
                    asm volatile("global_store_dword %0, %1, off sc0 sc1"
                                 : : "v"((void*)((unsigned int*)hW + sidx32)), "v"(hv.u) : "memory");
            }
            xcur = xnext;

            // --- drain stores, join waves, publish ---
            asm volatile("s_waitcnt vmcnt(0)" ::: "memory");
            __syncthreads();
            if constexpr (FAST) {
                // plain sc0 store (no RMW chain): flag[jt2] = t+1 after ALL
                // of this WG's h stores are L2-visible (drain before join).
                if (tid == 0) {
                    unsigned v = (unsigned)(t + 1);
                    asm volatile("global_store_dword %0, %1, off sc0"
                                 : : "v"((void*)(flags + jt2)), "v"(v) : "memory");
                }
                // no trailing sync: waves gate themselves on flags next step
            } else {
                if (tid == 0) {
                    unsigned target = 32u * (unsigned)(t + 1);
                    __hip_atomic_fetch_add(grp, 1u, __ATOMIC_RELAXED,
                                           __HIP_MEMORY_SCOPE_AGENT);
                    while (spin_budget &&
                           __hip_atomic_load(grp, __ATOMIC_RELAXED,
                                             __HIP_MEMORY_SCOPE_AGENT) < target) {
                        __builtin_amdgcn_s_sleep(1);
                        --spin_budget;
                    }
                }
                __syncthreads();
            }
        }
    };
    if (fastmode) mainloop(std::integral_constant<bool, true>{});
    else          mainloop(std::integral_constant<bool, false>{});

    // --- final FC (h final in buffer 0): jt2==0 WGs, k4==0 waves ---
    if (jt2 == 0 && k4 == 0) {
        if (fastmode) {
            // wait for ALL 32 producers' final stores (flag >= 512)
            unsigned int* fb = flags + (lane & 31);
            while (spin_budget) {
                unsigned f;
                asm volatile("global_load_dword %0, %1, off sc1\n\t"
                             "s_waitcnt vmcnt(0)"
                             : "=v"(f) : "v"(fb) : "memory");
                if (__all((int)(f >= (unsigned)TT))) break;
                __builtin_amdgcn_s_sleep(1);
                --spin_budget;
            }
        }
        const unsigned long long* hF = hbase;   // buffer 0
#pragma unroll 1
        for (int rr = 0; rr < 16; ++rr) {
            int row = gm * 32 + m2 * 16 + rr;
            int boff = row;                     // boff == M
            float s = 0.f;
#pragma unroll 1
            for (int uu = 0; uu < 4; ++uu) {
                int U = uu * 64 + lane;
                unsigned long long u;
                if (fastmode) {
                    asm volatile("global_load_dwordx2 %0, %1, off sc1\n\ts_waitcnt vmcnt(0)"
                                 : "=v"(u) : "v"(&hF[(size_t)U * 256 + boff]) : "memory");
                } else {
                    u = __hip_atomic_load((unsigned long long*)&hF[(size_t)U * 256 + boff],
                                          __ATOMIC_RELAXED, __HIP_MEMORY_SCOPE_AGENT);
                }
                int kb = (U >> 3) * 32 + ((U >> 1) & 3) * 8 + (U & 1) * 4;
                union { _Float16 h[4]; unsigned long long x; } v;
                v.x = u;
                float4 wf = *(const float4*)(W_fc + kb);
                s += (float)v.h[0] * wf.x + (float)v.h[1] * wf.y +
                     (float)v.h[2] * wf.z + (float)v.h[3] * wf.w;
            }
#pragma unroll
            for (int off = 32; off > 0; off >>= 1) s += __shfl_xor(s, off);
            if (lane == 0) out[row] = s + b_fc[0];
        }
    }
}

extern "C" void kernel_launch(void* const* d_in, const int* in_sizes, int n_in,
                              void* d_out, int out_size, void* d_ws, size_t ws_size,
                              hipStream_t stream) {
    const float* y_hist = (const float*)d_in[0];
    const float* W_ih   = (const float*)d_in[1];
    const float* W_hh   = (const float*)d_in[2];
    const float* b_ih   = (const float*)d_in[3];
    const float* b_hh   = (const float*)d_in[4];
    const float* W_fc   = (const float*)d_in[5];
    const float* b_fc   = (const float*)d_in[6];
    const float* h0     = (const float*)d_in[7];
    const float* c0     = (const float*)d_in[8];
    float* out = (float*)d_out;

    // ws: Wp fp16 (8 MB) | h buffers 2 x 512 KB | cnt (2 KB)
    unsigned short* Wp = (unsigned short*)d_ws;
    unsigned long long* hbase = (unsigned long long*)(Wp + (size_t)4194304);
    unsigned int* cnt = (unsigned int*)(hbase + 2 * HP_U64);

    pack_w<<<2048, 256, 0, stream>>>(W_hh, Wp);
    prep_state<<<256, 256, 0, stream>>>(h0, hbase, cnt);

    // 256 WGs x 512 threads, 160 KiB LDS -> 1 WG/CU, all co-resident
    lstm_persist<<<256, 512, 0, stream>>>(y_hist, W_ih, b_ih, b_hh, c0, W_fc, b_fc,
                                          Wp, hbase, cnt, out);
}

// Round 15
// 1824.230 us; speedup vs baseline: 1.6598x; 1.0217x over previous
//
#include <hip/hip_runtime.h>
#include <hip/hip_bf16.h>
#include <type_traits>

// LSTM decoder B=256, T=512, H=1024 — persistent fp16 MFMA, v18.
// Base = v17 (1863.9 us WIN; cumulative -26% from 2525.6). ONE change:
// reduction collapsed 3 rounds -> 2. Previously round 3 had wave k4=0
// read-add-write-swizzled (serial, 6/8 waves idle, ~300-500cy) + an extra
// sync. Now BOTH k4=0 and k4=1 write their 2-quarter partials SWIZZLED into
// their own slot after the round-1 add; the epilogue reads TWO slots and
// adds (8 extra scalar LDS reads/thread, parallel across all waves).
// Deletes 1 syncthreads + the serial round-3. Hazard audit: swizzled write
// of acc[a] stays in the same 256-float block as the round-1 read of acc[a]
// (ordered by the acc[a] register dep; a-blocks disjoint; slot private to
// its wave); post-epilogue sync still guards next step's round-1 writes.
// Swizzle identity (ml^sw)+r == (ml+r)^sw is v8-proven, applied per-slot.

#define BB 256
#define TT 512
#define HH 1024

typedef __attribute__((ext_vector_type(8))) short short8;
typedef __attribute__((ext_vector_type(8))) _Float16 half8;
typedef __attribute__((ext_vector_type(4))) float float4v;

#define HP_U64 ((size_t)65536)   // u64 per h buffer: 256 U-units x 256 rows

__device__ __forceinline__ float sigf(float x) { return 1.0f / (1.0f + __expf(-x)); }
__device__ __forceinline__ float tanhff(float x) {
    return 1.0f - 2.0f / (__expf(2.0f * x) + 1.0f);
}

// ---- pack W_hh (4096x1024 f32) -> fp16 B-fragment order ----
// Wp[jt2(32)][kc(32)][g(4)][nt(2)][lane(64)][8] ; per-jt2 block = 256 KB
__global__ __launch_bounds__(256) void pack_w(const float* __restrict__ W_hh,
                                              unsigned short* __restrict__ Wp) {
    int fid = blockIdx.x * 256 + threadIdx.x;   // 0..524287
    int lane = fid & 63;
    int nt = (fid >> 6) & 1;
    int g = (fid >> 7) & 3;
    int kc = (fid >> 9) & 31;
    int jt2 = fid >> 14;
    int j = jt2 * 32 + nt * 16 + (lane & 15);
    int row = g * HH + j;
    int k = kc * 32 + (lane >> 4) * 8;
    const float* src = W_hh + (size_t)row * HH + k;
    union { _Float16 h[8]; short8 s; } u;
#pragma unroll
    for (int e = 0; e < 8; ++e) u.h[e] = (_Float16)src[e];
    *(short8*)(Wp + (size_t)fid * 8) = u.s;
}

// ---- h0 -> fp16 fragment layout in buffer 0; zero flags + counters ----
// unit U=(k>>5)*8+((k>>2)&7); u64 idx = U*256 + M  (boff == M)
// cnt layout (u32): [0..255] = flags[gm*32+jt2] (0 => h_0 ready);
//                   [256+gm*8+{0,1,2}] = {safe barrier, xcd mask, arrive}
__global__ __launch_bounds__(256) void prep_state(const float* __restrict__ h0,
                                                  unsigned long long* __restrict__ hb0,
                                                  unsigned int* __restrict__ cnt) {
    int gid = blockIdx.x * 256 + threadIdx.x;   // 0..65535
    int r = gid & 255;
    int U = gid >> 8;
    int kb = (U >> 3) * 32 + ((U >> 1) & 3) * 8 + (U & 1) * 4;
    float4 v = *(const float4*)(h0 + (size_t)r * HH + kb);
    union { _Float16 h[4]; unsigned long long u; } x;
    x.h[0] = (_Float16)v.x; x.h[1] = (_Float16)v.y;
    x.h[2] = (_Float16)v.z; x.h[3] = (_Float16)v.w;
    hb0[(size_t)U * 256 + r] = x.u;
    if (blockIdx.x == 0) {
        cnt[threadIdx.x] = 0;          // flags
        cnt[256 + threadIdx.x] = 0;    // counters region
    }
}

// ---- persistent LSTM kernel: all 512 steps + final FC ----
__global__ __launch_bounds__(512, 1) void lstm_persist(
    const float* __restrict__ y_hist,
    const float* __restrict__ W_ih,           // (4096) flat
    const float* __restrict__ b_ih,
    const float* __restrict__ b_hh,
    const float* __restrict__ c0,             // (B,H) f32
    const float* __restrict__ W_fc,           // (H)
    const float* __restrict__ b_fc,           // (1)
    const unsigned short* __restrict__ Wp,    // packed fp16 W fragments
    unsigned long long* hbase,                // 2 buffers x HP_U64 u64
    unsigned int* cnt,
    float* __restrict__ out)
{
    __shared__ __align__(16) unsigned short Wlds[65536];   // 128 KB: gates 0,1
    __shared__ __align__(16) float scr[8192];              // 32 KB: 4 slots x 2048
    // 160 KiB exactly -> 1 WG/CU; grid=256 => all WGs co-resident

    const int tid = threadIdx.x;
    const int lane = tid & 63;
    const int wv = tid >> 6;
    const int m2 = wv & 1;                     // m half (16 rows)
    const int k4 = wv >> 1;                    // K quarter (256 k)
    const int bid = blockIdx.x;
    const int gm = bid & 7;                    // m-group == XCD id (round-robin)
    const int jt2 = bid >> 3;                  // 32-j tile

    const unsigned short* WpJ = Wp + (size_t)jt2 * 131072;

    // --- LDS: gates 0,1 fragments (all kc) ---
    for (int f = tid; f < 8192; f += 512) {
        int kc = f >> 8, g = (f >> 7) & 1, low = f & 127;
        *(short8*)&Wlds[(size_t)((kc * 2 + g) * 128 + low) * 8] =
            *(const short8*)(WpJ + (size_t)((kc * 4 + g) * 128 + low) * 8);
    }
    // --- registers: gates 2,3 fragments for this wave's K-quarter ---
    half8 Breg[8][2][2];   // [kc_l][g-2][nt]
#pragma unroll
    for (int kc_l = 0; kc_l < 8; ++kc_l) {
        int kc = k4 * 8 + kc_l;
#pragma unroll
        for (int g2 = 0; g2 < 2; ++g2)
#pragma unroll
            for (int nt = 0; nt < 2; ++nt)
                Breg[kc_l][g2][nt] = *(const half8*)
                    (WpJ + (size_t)((((kc * 4 + 2 + g2) * 2 + nt) * 64 + lane)) * 8);
    }

    // --- A addressing ---
    const int blk = gm * 2 + m2;               // 16-row block 0..15
    const int q = lane >> 4;
    const size_t abase = (size_t)blk * 16 + (lane & 15);
    const size_t qoff = (size_t)q * 512;

    // --- epilogue constants (ALL 512 threads: cell = 1 row x 2 j) ---
    const int em = tid & 31;                   // tile-local row
    const int jp = tid >> 5;                   // j-pair 0..15
    const int jq = jp >> 1;
    const int M = gm * 32 + em;
    float wi_[4][2], bs_[4][2], c_[2];
#pragma unroll
    for (int g = 0; g < 4; ++g)
#pragma unroll
        for (int jj = 0; jj < 2; ++jj) {
            int j = jt2 * 32 + jp * 2 + jj;
            wi_[g][jj] = W_ih[g * HH + j];
            bs_[g][jj] = b_ih[g * HH + j] + b_hh[g * HH + j];
        }
#pragma unroll
    for (int jj = 0; jj < 2; ++jj)
        c_[jj] = c0[(size_t)M * HH + jt2 * 32 + jp * 2 + jj];
    // u32 store index: ((jt2*8+jq)*256 + M)*2 + (jp&1); wave = full 256B line
    const size_t sidx32 = ((size_t)(jt2 * 8 + jq) * 256 + M) * 2 + (jp & 1);

    __syncthreads();   // Wlds visible

    unsigned int* flags = cnt + gm * 32;              // 32 flags, one per jt2
    unsigned int* grp = cnt + 256 + gm * 8;           // [0]=bar [1]=mask [2]=arrive
    const int ml = q * 4;                      // local row base within 16-row tile

    // --- spin budget: hang-proofing (v10.3-proven) ---
    unsigned spin_budget = 1u << 20;

    // --- XCD-uniformity detection (device-scope, once). Bailout -> SAFE. ---
    if (tid == 0) {
        unsigned myxcd;
        asm volatile("s_getreg_b32 %0, hwreg(HW_REG_XCC_ID)" : "=s"(myxcd));
        __hip_atomic_fetch_or(grp + 1, 1u << (myxcd & 31u),
                              __ATOMIC_RELAXED, __HIP_MEMORY_SCOPE_AGENT);
        __hip_atomic_fetch_add(grp + 2, 1u,
                               __ATOMIC_RELAXED, __HIP_MEMORY_SCOPE_AGENT);
        int ok = 0;
        while (spin_budget) {
            if (__hip_atomic_load(grp + 2, __ATOMIC_RELAXED,
                                  __HIP_MEMORY_SCOPE_AGENT) >= 32u) { ok = 1; break; }
            __builtin_amdgcn_s_sleep(1);
            --spin_budget;
        }
        unsigned mm = __hip_atomic_load(grp + 1, __ATOMIC_RELAXED,
                                        __HIP_MEMORY_SCOPE_AGENT);
        ((volatile int*)scr)[0] = (ok && ((mm & (mm - 1u)) == 0u)) ? 1 : 0;
    }
    __syncthreads();
    const bool fastmode = (((volatile int*)scr)[0] != 0);
    __syncthreads();   // flag captured before scr reuse

    auto mainloop = [&](auto FASTC) {
        constexpr bool FAST = decltype(FASTC)::value;
        // x rotated one step ahead: gate poll must see NO unrelated VMEM.
        float xcur = y_hist[(size_t)M * TT];
        for (int t = 0; t < TT; ++t) {
            const unsigned long long* hR = hbase + (size_t)(t & 1) * HP_U64;
            unsigned long long* hW = hbase + (size_t)((t + 1) & 1) * HP_U64;

            float4v acc[8] = {{0.f,0.f,0.f,0.f},{0.f,0.f,0.f,0.f},{0.f,0.f,0.f,0.f},
                              {0.f,0.f,0.f,0.f},{0.f,0.f,0.f,0.f},{0.f,0.f,0.f,0.f},
                              {0.f,0.f,0.f,0.f},{0.f,0.f,0.f,0.f}};

            if constexpr (FAST) {
                // --- dataflow gate: wave k4 needs ONLY producers jt2 in
                //     [8*k4, 8*k4+8) at flag >= t. Sleepless poll (budgeted);
                //     "memory" clobber orders the ring loads after the gate. ---
                unsigned int* fp = flags + k4 * 8 + (lane & 7);
                const unsigned need = (unsigned)t;
                while (spin_budget) {
                    unsigned f;
                    asm volatile("global_load_dword %0, %1, off sc1\n\t"
                                 "s_waitcnt vmcnt(0)"
                                 : "=v"(f) : "v"(fp) : "memory");
                    if (__all((int)(f >= need))) break;
                    --spin_budget;
                }
            }
            // --- ring loads: agent atomic loads in BOTH modes (counted
            //     per-chunk vmcnt + ds_read pipelining by the compiler). ---
            unsigned long long ring[8][2];
#pragma unroll
            for (int p = 0; p < 8; ++p) {
                size_t ua = (size_t)(k4 * 8 + p) * 2048 + qoff + abase;
                ring[p][0] = __hip_atomic_load((unsigned long long*)&hR[ua],
                                               __ATOMIC_RELAXED, __HIP_MEMORY_SCOPE_AGENT);
                ring[p][1] = __hip_atomic_load((unsigned long long*)&hR[ua + 256],
                                               __ATOMIC_RELAXED, __HIP_MEMORY_SCOPE_AGENT);
            }
            // prefetch next-step x here: latency hides under MFMA; drained by
            // the epilogue vmcnt(0) -> NOT pending at the next gate poll.
            float xnext = y_hist[(size_t)M * TT + (t + 1 < TT ? t + 1 : TT - 1)];
#pragma unroll
            for (int ch = 0; ch < 8; ++ch) {
                union { unsigned long long u[2]; half8 h; } af;
                af.u[0] = ring[ch][0];
                af.u[1] = ring[ch][1];
                const int kc = k4 * 8 + ch;
#pragma unroll
                for (int g = 0; g < 2; ++g)
#pragma unroll
                    for (int nt = 0; nt < 2; ++nt) {
                        half8 bh = *(const half8*)
                            &Wlds[(size_t)((kc * 2 + g) * 128 + nt * 64 + lane) * 8];
                        acc[g * 2 + nt] =
                            __builtin_amdgcn_mfma_f32_16x16x32_f16(af.h, bh, acc[g * 2 + nt], 0, 0, 0);
                    }
#pragma unroll
                for (int g2 = 0; g2 < 2; ++g2)
#pragma unroll
                    for (int nt = 0; nt < 2; ++nt)
                        acc[(2 + g2) * 2 + nt] =
                            __builtin_amdgcn_mfma_f32_16x16x32_f16(af.h, Breg[ch][g2][nt],
                                                                   acc[(2 + g2) * 2 + nt], 0, 0, 0);
            }

            // --- 4-way k-reduction, 2 rounds (v18): k4>=2 write contiguous;
            //     k4<2 add, then BOTH write swizzled partials to own slot.
            //     Epilogue dual-reads slots m2*2 and m2*2+1 and adds. ---
            if (k4 >= 2) {
                int sb = (m2 * 2 + (k4 & 1)) * 2048;
#pragma unroll
                for (int a = 0; a < 8; ++a)
                    *(float4v*)&scr[sb + a * 256 + lane * 4] = acc[a];
            }
            __syncthreads();
            if (k4 < 2) {
                int sb = (m2 * 2 + k4) * 2048;
#pragma unroll
                for (int a = 0; a < 8; ++a)
                    acc[a] += *(const float4v*)&scr[sb + a * 256 + lane * 4];
                // swizzled partial write (same slot; per-a block identical to
                // the read block -> ordered by acc[a] dependency, no hazard)
#pragma unroll
                for (int a = 0; a < 8; ++a) {
                    int n = (a >> 1) * 32 + (a & 1) * 16 + (lane & 15);
                    int sw = n * 16 + (ml ^ ((n & 3) << 2));
                    *(float4v*)&scr[sb + sw] = acc[a];
                }
            }
            __syncthreads();

            // --- epilogue (all 512 threads): 1 row x 2 j; dual-slot read ---
            {
                int rbase = (em >> 4) * 2 * 2048;
                union { _Float16 h[2]; unsigned int u; } hv;
#pragma unroll
                for (int jj = 0; jj < 2; ++jj) {
                    int jl = jp * 2 + jj;                      // 0..31
                    int msw = (em & 15) ^ ((jl & 3) << 2);
                    float gi = scr[rbase + (0 * 32 + jl) * 16 + msw]
                             + scr[rbase + 2048 + (0 * 32 + jl) * 16 + msw]
                             + xcur * wi_[0][jj] + bs_[0][jj];
                    float gf = scr[rbase + (1 * 32 + jl) * 16 + msw]
                             + scr[rbase + 2048 + (1 * 32 + jl) * 16 + msw]
                             + xcur * wi_[1][jj] + bs_[1][jj];
                    float gg = scr[rbase + (2 * 32 + jl) * 16 + msw]
                             + scr[rbase + 2048 + (2 * 32 + jl) * 16 + msw]
                             + xcur * wi_[2][jj] + bs_[2][jj];
                    float go = scr[rbase + (3 * 32 + jl) * 16 + msw]
                             + scr[rbase + 2048 + (3 * 32 + jl) * 16 + msw]
                             + xcur * wi_[3][jj] + bs_[3][jj];
                    float cn = sigf(gf) * c_[jj] + sigf(gi) * tanhff(gg);
                    float hn = sigf(go) * tanhff(cn);
                    c_[jj] = cn;
                    hv.h[jj] = (_Float16)hn;
                }
                if constexpr (FAST)
                    asm volatile("global_store_dword %0, %1, off sc0"
                                 : : "v"((void*)((unsigned int*)hW + sidx32)), "v"(hv.u) : "memory");
                else
                    asm volatile("global_store_dword %0, %1, off sc0 sc1"
                                 : : "v"((void*)((unsigned int*)hW + sidx32)), "v"(hv.u) : "memory");
            }
            xcur = xnext;

            // --- drain stores, join waves, publish ---
            asm volatile("s_waitcnt vmcnt(0)" ::: "memory");
            __syncthreads();
            if constexpr (FAST) {
                // plain sc0 store (no RMW chain): flag[jt2] = t+1 after ALL
                // of this WG's h stores are L2-visible (drain before join).
                if (tid == 0) {
                    unsigned v = (unsigned)(t + 1);
                    asm volatile("global_store_dword %0, %1, off sc0"
                                 : : "v"((void*)(flags + jt2)), "v"(v) : "memory");
                }
                // no trailing sync: waves gate themselves on flags next step
            } else {
                if (tid == 0) {
                    unsigned target = 32u * (unsigned)(t + 1);
                    __hip_atomic_fetch_add(grp, 1u, __ATOMIC_RELAXED,
                                           __HIP_MEMORY_SCOPE_AGENT);
                    while (spin_budget &&
                           __hip_atomic_load(grp, __ATOMIC_RELAXED,
                                             __HIP_MEMORY_SCOPE_AGENT) < target) {
                        __builtin_amdgcn_s_sleep(1);
                        --spin_budget;
                    }
                }
                __syncthreads();
            }
        }
    };
    if (fastmode) mainloop(std::integral_constant<bool, true>{});
    else          mainloop(std::integral_constant<bool, false>{});

    // --- final FC (h final in buffer 0): jt2==0 WGs, k4==0 waves ---
    if (jt2 == 0 && k4 == 0) {
        if (fastmode) {
            // wait for ALL 32 producers' final stores (flag >= 512)
            unsigned int* fb = flags + (lane & 31);
            while (spin_budget) {
                unsigned f;
                asm volatile("global_load_dword %0, %1, off sc1\n\t"
                             "s_waitcnt vmcnt(0)"
                             : "=v"(f) : "v"(fb) : "memory");
                if (__all((int)(f >= (unsigned)TT))) break;
                __builtin_amdgcn_s_sleep(1);
                --spin_budget;
            }
        }
        const unsigned long long* hF = hbase;   // buffer 0
#pragma unroll 1
        for (int rr = 0; rr < 16; ++rr) {
            int row = gm * 32 + m2 * 16 + rr;
            int boff = row;                     // boff == M
            float s = 0.f;
#pragma unroll 1
            for (int uu = 0; uu < 4; ++uu) {
                int U = uu * 64 + lane;
                unsigned long long u;
                if (fastmode) {
                    asm volatile("global_load_dwordx2 %0, %1, off sc1\n\ts_waitcnt vmcnt(0)"
                                 : "=v"(u) : "v"(&hF[(size_t)U * 256 + boff]) : "memory");
                } else {
                    u = __hip_atomic_load((unsigned long long*)&hF[(size_t)U * 256 + boff],
                                          __ATOMIC_RELAXED, __HIP_MEMORY_SCOPE_AGENT);
                }
                int kb = (U >> 3) * 32 + ((U >> 1) & 3) * 8 + (U & 1) * 4;
                union { _Float16 h[4]; unsigned long long x; } v;
                v.x = u;
                float4 wf = *(const float4*)(W_fc + kb);
                s += (float)v.h[0] * wf.x + (float)v.h[1] * wf.y +
                     (float)v.h[2] * wf.z + (float)v.h[3] * wf.w;
            }
#pragma unroll
            for (int off = 32; off > 0; off >>= 1) s += __shfl_xor(s, off);
            if (lane == 0) out[row] = s + b_fc[0];
        }
    }
}

extern "C" void kernel_launch(void* const* d_in, const int* in_sizes, int n_in,
                              void* d_out, int out_size, void* d_ws, size_t ws_size,
                              hipStream_t stream) {
    const float* y_hist = (const float*)d_in[0];
    const float* W_ih   = (const float*)d_in[1];
    const float* W_hh   = (const float*)d_in[2];
    const float* b_ih   = (const float*)d_in[3];
    const float* b_hh   = (const float*)d_in[4];
    const float* W_fc   = (const float*)d_in[5];
    const float* b_fc   = (const float*)d_in[6];
    const float* h0     = (const float*)d_in[7];
    const float* c0     = (const float*)d_in[8];
    float* out = (float*)d_out;

    // ws: Wp fp16 (8 MB) | h buffers 2 x 512 KB | cnt (2 KB)
    unsigned short* Wp = (unsigned short*)d_ws;
    unsigned long long* hbase = (unsigned long long*)(Wp + (size_t)4194304);
    unsigned int* cnt = (unsigned int*)(hbase + 2 * HP_U64);

    pack_w<<<2048, 256, 0, stream>>>(W_hh, Wp);
    prep_state<<<256, 256, 0, stream>>>(h0, hbase, cnt);

    // 256 WGs x 512 threads, 160 KiB LDS -> 1 WG/CU, all co-resident
    lstm_persist<<<256, 512, 0, stream>>>(y_hist, W_ih, b_ih, b_hh, c0, W_fc, b_fc,
                                          Wp, hbase, cnt, out);
}